// Round 9
// baseline (96.872 us; speedup 1.0000x reference)
//
#include <hip/hip_runtime.h>
#include <hip/hip_bf16.h>
#include <stdint.h>

typedef float f32x16 __attribute__((ext_vector_type(16)));
typedef float f32x4  __attribute__((ext_vector_type(4)));
typedef short s16x8  __attribute__((ext_vector_type(8)));
typedef unsigned int u32x4 __attribute__((ext_vector_type(4)));

#define HWSZ   4096
#define NBATCH 4
#define LOG2E  1.44269504088896340736f

__device__ __forceinline__ unsigned short f2bf(float f) {
    unsigned u = __builtin_bit_cast(unsigned, f);
    u += 0x7FFFu + ((u >> 16) & 1u);          // RTNE
    return (unsigned short)(u >> 16);
}
__device__ __forceinline__ unsigned cvt_pk_bf16(float lo, float hi) {
    __hip_bfloat162 h = __float22bfloat162_rn(make_float2(lo, hi));
    return *reinterpret_cast<unsigned*>(&h);   // v_cvt_pk_bf16_f32
}

// ---------------- Kernel 1: MFMA projections ----------------
// xq = x@W1 + b1 -> d_out (f32 residual) + xq_bf (bf16, PRE-SCALED by log2e: K-only)
// yk = y@W2 + b2 -> yk_bf (bf16) + ykT_bf (bf16 transposed)
__global__ __launch_bounds__(256, 1) void proj_kernel(
    const float* __restrict__ x, const float* __restrict__ y,
    const float* __restrict__ W1, const float* __restrict__ b1,
    const float* __restrict__ W2, const float* __restrict__ b2,
    float* __restrict__ xq_f32,
    unsigned short* __restrict__ xq_bf,
    unsigned short* __restrict__ yk_bf,
    unsigned short* __restrict__ ykT_bf)
{
    __shared__ unsigned short Xlds[64][136];
    __shared__ unsigned short Ylds[64][136];
    __shared__ unsigned short Tlds[128][72];

    const int t    = threadIdx.x;
    const int lane = t & 63;
    const int w    = t >> 6;
    const int l31  = lane & 31;
    const int g    = lane >> 5;
    const int r0   = blockIdx.x * 64;
    const int b    = r0 >> 12;
    const int j0   = r0 & (HWSZ - 1);

    #pragma unroll
    for (int i = 0; i < 8; ++i) {
        int li = t + 256 * i;
        int row = li >> 5, c = (li & 31) * 4;
        float4 vx = *(const float4*)(x + (size_t)(r0 + row) * 128 + c);
        float4 vy = *(const float4*)(y + (size_t)(r0 + row) * 128 + c);
        *(uint2*)&Xlds[row][c] = make_uint2(cvt_pk_bf16(vx.x, vx.y), cvt_pk_bf16(vx.z, vx.w));
        *(uint2*)&Ylds[row][c] = make_uint2(cvt_pk_bf16(vy.x, vy.y), cvt_pk_bf16(vy.z, vy.w));
    }
    __syncthreads();

    const int m  = w >> 1;
    const int fh = w & 1;
    const float* Wm = m ? W2 : W1;
    const float* bm = m ? b2 : b1;
    const unsigned short* A0 = m ? &Ylds[0][0] : &Xlds[0][0];

    f32x16 acc[2][2];
    #pragma unroll
    for (int i = 0; i < 16; ++i) {
        acc[0][0][i] = 0.f; acc[0][1][i] = 0.f;
        acc[1][0][i] = 0.f; acc[1][1][i] = 0.f;
    }

    #pragma unroll
    for (int ks = 0; ks < 8; ++ks) {
        s16x8 bfr[2];
        #pragma unroll
        for (int ft = 0; ft < 2; ++ft) {
            const float* wp = Wm + (size_t)(ks * 16 + g * 8) * 128 + fh * 64 + ft * 32 + l31;
            #pragma unroll
            for (int i = 0; i < 8; ++i)
                bfr[ft][i] = (short)f2bf(wp[(size_t)i * 128]);
        }
        #pragma unroll
        for (int rt = 0; rt < 2; ++rt) {
            s16x8 af = *(const s16x8*)(A0 + (size_t)(rt * 32 + l31) * 136 + ks * 16 + g * 8);
            acc[rt][0] = __builtin_amdgcn_mfma_f32_32x32x16_bf16(af, bfr[0], acc[rt][0], 0, 0, 0);
            acc[rt][1] = __builtin_amdgcn_mfma_f32_32x32x16_bf16(af, bfr[1], acc[rt][1], 0, 0, 0);
        }
    }

    const float bias_v[2] = { bm[fh * 64 + l31], bm[fh * 64 + 32 + l31] };

    if (m == 0) {
        #pragma unroll
        for (int rt = 0; rt < 2; ++rt)
        #pragma unroll
        for (int ft = 0; ft < 2; ++ft) {
            int f = fh * 64 + ft * 32 + l31;
            #pragma unroll
            for (int r = 0; r < 16; ++r) {
                int row = rt * 32 + (r & 3) + 8 * (r >> 2) + 4 * g;
                float v = acc[rt][ft][r] + bias_v[ft];
                size_t o = (size_t)(r0 + row) * 128 + f;
                xq_f32[o] = v;
                xq_bf[o]  = f2bf(v * LOG2E);      // K pre-scaled for exp2 sigmoid
            }
        }
    } else {
        #pragma unroll
        for (int rt = 0; rt < 2; ++rt)
        #pragma unroll
        for (int ft = 0; ft < 2; ++ft) {
            int f = fh * 64 + ft * 32 + l31;
            #pragma unroll
            for (int rg = 0; rg < 4; ++rg) {
                float p0 = acc[rt][ft][4 * rg + 0] + bias_v[ft];
                float p1 = acc[rt][ft][4 * rg + 1] + bias_v[ft];
                float p2 = acc[rt][ft][4 * rg + 2] + bias_v[ft];
                float p3 = acc[rt][ft][4 * rg + 3] + bias_v[ft];
                int jb = rt * 32 + 8 * rg + 4 * g;
                *(uint2*)&Tlds[f][jb] = make_uint2(cvt_pk_bf16(p0, p1), cvt_pk_bf16(p2, p3));
                size_t o = (size_t)(r0 + jb) * 128 + f;
                yk_bf[o]       = f2bf(p0);
                yk_bf[o + 128] = f2bf(p1);
                yk_bf[o + 256] = f2bf(p2);
                yk_bf[o + 384] = f2bf(p3);
            }
        }
    }
    __syncthreads();

    {
        int f  = t >> 1;
        int jh = (t & 1) * 32;
        unsigned short* dst = ykT_bf + ((size_t)(b * 128 + f)) * HWSZ + j0 + jh;
        #pragma unroll
        for (int c = 0; c < 4; ++c)
            *(s16x8*)(dst + c * 8) = *(const s16x8*)&Tlds[f][jh + c * 8];
    }
}

// ---------------- shared attention LDS geometry ----------------
#define KT_STR   136
#define VT_STR   72
#define KT_BYTES (64 * KT_STR * 2)     // 17408
#define VT_BYTES (128 * VT_STR * 2)    // 18432
#define BUF_BYTES (KT_BYTES + VT_BYTES)

// ---------------- Kernel 2a: QBLK=128, single-K + V-dbuf, 6 uneven splits ----
// LDS = 17408 (K single) + 2*18432 (V dbuf) = 54272 <= 54613 -> 3 WG/CU.
// Regs: ~96 VGPR + 64 AGPR = 160 <= 170 -> 3 waves/SIMD. Grid 768 = 3/CU exact.
// Two barriers/iter: [compute reads K,V[c]] barrier [write K-next,V[c^1]] barrier.
__global__ __launch_bounds__(256, 3) void attn128s6_kernel(
    const unsigned short* __restrict__ Kbf,   // xq_bf (log2e-scaled) [b][j][128]
    const unsigned short* __restrict__ Qbf,   // yk_bf  [b][q][128]
    const unsigned short* __restrict__ Vtbf,  // ykT_bf [b][128][4096]
    float* __restrict__ outp)                 // partials base (6 x NELEM)
{
    __shared__ __align__(16) unsigned short Klds[64 * KT_STR];       // 17408 B
    __shared__ __align__(16) unsigned short Vlds[2][128 * VT_STR];   // 36864 B

    const int t    = threadIdx.x;
    const int lane = t & 63;
    const int qt   = t >> 6;
    const int l31  = lane & 31;
    const int g    = lane >> 5;

    const int split = blockIdx.x >> 7;        // 0..5
    const int r     = blockIdx.x & 127;
    const int b     = r >> 5;
    const int qb    = (r & 31) * 128;
    // uneven split: tiles {11,11,11,11,10,10}, starts {0,11,22,33,44,54}
    const int st    = 11 * split - (split > 4 ? split - 4 : 0);
    const int nt    = (split >= 4) ? 10 : 11;
    const int jBegin = st * 64;

    s16x8 qfrag[8];
    {
        const unsigned short* qp =
            Qbf + (((size_t)(b * HWSZ + qb + 32 * qt + l31)) << 7) + g * 8;
        #pragma unroll
        for (int fs = 0; fs < 8; ++fs)
            qfrag[fs] = *(const s16x8*)(qp + fs * 16);
    }

    f32x16 acc[4];
    #pragma unroll
    for (int ft = 0; ft < 4; ++ft)
        #pragma unroll
        for (int i = 0; i < 16; ++i) acc[ft][i] = 0.f;

    const unsigned short* Kbase = Kbf  + (((size_t)b * HWSZ) << 7);
    const unsigned short* Vbase = Vtbf + (((size_t)b) << 7) * HWSZ;

    const unsigned short* kSrc = Kbase + (size_t)(jBegin + (t >> 4)) * 128 + (t & 15) * 8;
    const unsigned short* vSrc = Vbase + (size_t)(t >> 3) * HWSZ + jBegin + (t & 7) * 8;
    const int kDst = (t >> 4) * KT_STR + (t & 15) * 8;
    const int vDst = (t >> 3) * VT_STR + (t & 7) * 8;

    {   // prologue: stage tile 0 (K -> Klds, V -> Vlds[0])
        #pragma unroll
        for (int i = 0; i < 4; ++i)
            *(s16x8*)(Klds + kDst + i * 16 * KT_STR) = *(const s16x8*)(kSrc + (size_t)i * 2048);
        #pragma unroll
        for (int i = 0; i < 4; ++i)
            *(s16x8*)(&Vlds[0][0] + vDst + i * 32 * VT_STR) = *(const s16x8*)(vSrc + (size_t)i * 32 * HWSZ);
    }
    __syncthreads();

    int c = 0;
    for (int it = 0; it < nt; ++it) {
        const bool pre = (it + 1 < nt);
        s16x8 kr[4], vr[4];
        if (pre) {                       // issue-early loads for tile it+1
            kSrc += 64 * 128;
            vSrc += 64;
            #pragma unroll
            for (int i = 0; i < 4; ++i)
                kr[i] = *(const s16x8*)(kSrc + (size_t)i * 2048);
            #pragma unroll
            for (int i = 0; i < 4; ++i)
                vr[i] = *(const s16x8*)(vSrc + (size_t)i * 32 * HWSZ);
        }

        const unsigned short* Vl = &Vlds[c][0];

        #pragma unroll
        for (int jt = 0; jt < 2; ++jt) {
            // ---- QK subtile: S'[32j][32q], dual-chain ----
            f32x16 sa, sb;
            #pragma unroll
            for (int i = 0; i < 16; ++i) { sa[i] = 0.f; sb[i] = 0.f; }
            const unsigned short* Krow = Klds + (size_t)(32 * jt + l31) * KT_STR + g * 8;
            __builtin_amdgcn_s_setprio(1);
            #pragma unroll
            for (int fs = 0; fs < 4; ++fs) {
                sa = __builtin_amdgcn_mfma_f32_32x32x16_bf16(
                         *(const s16x8*)(Krow + fs * 16), qfrag[fs], sa, 0, 0, 0);
                sb = __builtin_amdgcn_mfma_f32_32x32x16_bf16(
                         *(const s16x8*)(Krow + (fs + 4) * 16), qfrag[fs + 4], sb, 0, 0, 0);
            }
            __builtin_amdgcn_s_setprio(0);

            // ---- sigmoid via exp2 (K pre-scaled) + cvt_pk pack ----
            unsigned W0[4], W1[4];
            #pragma unroll
            for (int rg = 0; rg < 4; ++rg) {
                float s0 = sa[4 * rg + 0] + sb[4 * rg + 0];
                float s1 = sa[4 * rg + 1] + sb[4 * rg + 1];
                float s2v = sa[4 * rg + 2] + sb[4 * rg + 2];
                float s3 = sa[4 * rg + 3] + sb[4 * rg + 3];
                float p0 = __builtin_amdgcn_rcpf(1.f + __builtin_amdgcn_exp2f(-s0));
                float p1 = __builtin_amdgcn_rcpf(1.f + __builtin_amdgcn_exp2f(-s1));
                float p2 = __builtin_amdgcn_rcpf(1.f + __builtin_amdgcn_exp2f(-s2v));
                float p3 = __builtin_amdgcn_rcpf(1.f + __builtin_amdgcn_exp2f(-s3));
                W0[rg] = cvt_pk_bf16(p0, p1);
                W1[rg] = cvt_pk_bf16(p2, p3);
            }

            // ---- PV: A-frags via v_permlane32_swap_b32 ----
            #pragma unroll
            for (int s2 = 0; s2 < 2; ++s2) {
                unsigned a0 = W0[2 * s2], b0 = W0[2 * s2 + 1];
                unsigned a1 = W1[2 * s2], b1 = W1[2 * s2 + 1];
                asm("v_permlane32_swap_b32 %0, %1" : "+v"(a0), "+v"(b0));
                asm("v_permlane32_swap_b32 %0, %1" : "+v"(a1), "+v"(b1));
                u32x4 pw;
                pw[0] = a0; pw[1] = a1; pw[2] = b0; pw[3] = b1;
                s16x8 pf = __builtin_bit_cast(s16x8, pw);
                const int ks = 2 * jt + s2;
                __builtin_amdgcn_s_setprio(1);
                #pragma unroll
                for (int ft = 0; ft < 4; ++ft) {
                    s16x8 vf = *(const s16x8*)(Vl + (size_t)(32 * ft + l31) * VT_STR + ks * 16 + g * 8);
                    acc[ft] = __builtin_amdgcn_mfma_f32_32x32x16_bf16(pf, vf, acc[ft], 0, 0, 0);
                }
                __builtin_amdgcn_s_setprio(0);
            }
        }

        __syncthreads();                 // all waves done reading Klds / Vlds[c]
        if (pre) {                       // overwrite K, fill other V buffer
            #pragma unroll
            for (int i = 0; i < 4; ++i)
                *(s16x8*)(Klds + kDst + i * 16 * KT_STR) = kr[i];
            #pragma unroll
            for (int i = 0; i < 4; ++i)
                *(s16x8*)(&Vlds[c ^ 1][0] + vDst + i * 32 * VT_STR) = vr[i];
            __syncthreads();             // writes visible
        }
        c ^= 1;
    }

    // ---- epilogue: direct store of wave-private 32q x 128f partial ----
    float* op = outp + (size_t)split * ((size_t)NBATCH * HWSZ * 128);
    #pragma unroll
    for (int ft = 0; ft < 4; ++ft)
    #pragma unroll
    for (int r2 = 0; r2 < 16; ++r2) {
        int row = (r2 & 3) + 8 * (r2 >> 2) + 4 * g;
        int q = qb + 32 * qt + row;
        size_t o = (((size_t)(b * HWSZ + q)) << 7) + 32 * ft + l31;
        op[o] = acc[ft][r2];
    }
}

// ---------------- Kernel 2b: QBLK=128 4-split (R8-verified fallback) ----------
__global__ __launch_bounds__(256, 2) void attn128_kernel(
    const unsigned short* __restrict__ Kbf,
    const unsigned short* __restrict__ Qbf,
    const unsigned short* __restrict__ Vtbf,
    float* __restrict__ outp)
{
    __shared__ __align__(16) char smem[2 * BUF_BYTES];

    const int t    = threadIdx.x;
    const int lane = t & 63;
    const int qt   = t >> 6;
    const int l31  = lane & 31;
    const int g    = lane >> 5;

    const int split  = blockIdx.x >> 7;
    const int r      = blockIdx.x & 127;
    const int b      = r >> 5;
    const int qb     = (r & 31) * 128;
    const int jBegin = split * (HWSZ / 4);
    const int nt     = (HWSZ / 4) / 64;

    s16x8 qfrag[8];
    {
        const unsigned short* qp =
            Qbf + (((size_t)(b * HWSZ + qb + 32 * qt + l31)) << 7) + g * 8;
        #pragma unroll
        for (int fs = 0; fs < 8; ++fs)
            qfrag[fs] = *(const s16x8*)(qp + fs * 16);
    }

    f32x16 acc[4];
    #pragma unroll
    for (int ft = 0; ft < 4; ++ft)
        #pragma unroll
        for (int i = 0; i < 16; ++i) acc[ft][i] = 0.f;

    const unsigned short* Kbase = Kbf  + (((size_t)b * HWSZ) << 7);
    const unsigned short* Vbase = Vtbf + (((size_t)b) << 7) * HWSZ;

    const unsigned short* kSrc = Kbase + (size_t)(jBegin + (t >> 4)) * 128 + (t & 15) * 8;
    const unsigned short* vSrc = Vbase + (size_t)(t >> 3) * HWSZ + jBegin + (t & 7) * 8;
    const int kDst = (t >> 4) * KT_STR + (t & 15) * 8;
    const int vDst = (t >> 3) * VT_STR + (t & 7) * 8;

    {
        unsigned short* Kl = (unsigned short*)smem;
        unsigned short* Vl = (unsigned short*)(smem + KT_BYTES);
        #pragma unroll
        for (int i = 0; i < 4; ++i)
            *(s16x8*)(Kl + kDst + i * 16 * KT_STR) = *(const s16x8*)(kSrc + (size_t)i * 2048);
        #pragma unroll
        for (int i = 0; i < 4; ++i)
            *(s16x8*)(Vl + vDst + i * 32 * VT_STR) = *(const s16x8*)(vSrc + (size_t)i * 32 * HWSZ);
    }
    __syncthreads();

    int c = 0;
    for (int it = 0; it < nt; ++it) {
        const bool pre = (it + 1 < nt);
        s16x8 kr[4], vr[4];
        if (pre) {
            kSrc += 64 * 128;
            vSrc += 64;
            #pragma unroll
            for (int i = 0; i < 4; ++i)
                kr[i] = *(const s16x8*)(kSrc + (size_t)i * 2048);
            #pragma unroll
            for (int i = 0; i < 4; ++i)
                vr[i] = *(const s16x8*)(vSrc + (size_t)i * 32 * HWSZ);
        }

        const unsigned short* Kl = (const unsigned short*)(smem + c * BUF_BYTES);
        const unsigned short* Vl = (const unsigned short*)(smem + c * BUF_BYTES + KT_BYTES);

        #pragma unroll
        for (int jt = 0; jt < 2; ++jt) {
            f32x16 sa, sb;
            #pragma unroll
            for (int i = 0; i < 16; ++i) { sa[i] = 0.f; sb[i] = 0.f; }
            const unsigned short* Krow = Kl + (size_t)(32 * jt + l31) * KT_STR + g * 8;
            __builtin_amdgcn_s_setprio(1);
            #pragma unroll
            for (int fs = 0; fs < 4; ++fs) {
                sa = __builtin_amdgcn_mfma_f32_32x32x16_bf16(
                         *(const s16x8*)(Krow + fs * 16), qfrag[fs], sa, 0, 0, 0);
                sb = __builtin_amdgcn_mfma_f32_32x32x16_bf16(
                         *(const s16x8*)(Krow + (fs + 4) * 16), qfrag[fs + 4], sb, 0, 0, 0);
            }
            __builtin_amdgcn_s_setprio(0);

            unsigned W0[4], W1[4];
            #pragma unroll
            for (int rg = 0; rg < 4; ++rg) {
                float s0 = sa[4 * rg + 0] + sb[4 * rg + 0];
                float s1 = sa[4 * rg + 1] + sb[4 * rg + 1];
                float s2v = sa[4 * rg + 2] + sb[4 * rg + 2];
                float s3 = sa[4 * rg + 3] + sb[4 * rg + 3];
                float p0 = __builtin_amdgcn_rcpf(1.f + __builtin_amdgcn_exp2f(-s0));
                float p1 = __builtin_amdgcn_rcpf(1.f + __builtin_amdgcn_exp2f(-s1));
                float p2 = __builtin_amdgcn_rcpf(1.f + __builtin_amdgcn_exp2f(-s2v));
                float p3 = __builtin_amdgcn_rcpf(1.f + __builtin_amdgcn_exp2f(-s3));
                W0[rg] = cvt_pk_bf16(p0, p1);
                W1[rg] = cvt_pk_bf16(p2, p3);
            }

            #pragma unroll
            for (int s2 = 0; s2 < 2; ++s2) {
                unsigned a0 = W0[2 * s2], b0 = W0[2 * s2 + 1];
                unsigned a1 = W1[2 * s2], b1 = W1[2 * s2 + 1];
                asm("v_permlane32_swap_b32 %0, %1" : "+v"(a0), "+v"(b0));
                asm("v_permlane32_swap_b32 %0, %1" : "+v"(a1), "+v"(b1));
                u32x4 pw;
                pw[0] = a0; pw[1] = a1; pw[2] = b0; pw[3] = b1;
                s16x8 pf = __builtin_bit_cast(s16x8, pw);
                const int ks = 2 * jt + s2;
                __builtin_amdgcn_s_setprio(1);
                #pragma unroll
                for (int ft = 0; ft < 4; ++ft) {
                    s16x8 vf = *(const s16x8*)(Vl + (size_t)(32 * ft + l31) * VT_STR + ks * 16 + g * 8);
                    acc[ft] = __builtin_amdgcn_mfma_f32_32x32x16_bf16(pf, vf, acc[ft], 0, 0, 0);
                }
                __builtin_amdgcn_s_setprio(0);
            }
        }

        if (pre) {
            unsigned short* Kd = (unsigned short*)(smem + (c ^ 1) * BUF_BYTES);
            unsigned short* Vd = (unsigned short*)(smem + (c ^ 1) * BUF_BYTES + KT_BYTES);
            #pragma unroll
            for (int i = 0; i < 4; ++i)
                *(s16x8*)(Kd + kDst + i * 16 * KT_STR) = kr[i];
            #pragma unroll
            for (int i = 0; i < 4; ++i)
                *(s16x8*)(Vd + vDst + i * 32 * VT_STR) = vr[i];
        }
        __syncthreads();
        c ^= 1;
    }

    float* op = outp + (size_t)split * ((size_t)NBATCH * HWSZ * 128);
    #pragma unroll
    for (int ft = 0; ft < 4; ++ft)
    #pragma unroll
    for (int r2 = 0; r2 < 16; ++r2) {
        int row = (r2 & 3) + 8 * (r2 >> 2) + 4 * g;
        int q = qb + 32 * qt + row;
        size_t o = (((size_t)(b * HWSZ + q)) << 7) + 32 * ft + l31;
        op[o] = acc[ft][r2];
    }
}

// ---------------- Kernel 2c: QBLK=64 fallback (2-split / no-split) ----------------
template<bool SPLIT>
__global__ __launch_bounds__(256, 2) void attn_kernel(
    const unsigned short* __restrict__ Kbf,
    const unsigned short* __restrict__ Qbf,
    const unsigned short* __restrict__ Vtbf,
    const float* __restrict__ resid,
    float* __restrict__ outp)
{
    __shared__ __align__(16) char smem[2 * BUF_BYTES];

    const int t    = threadIdx.x;
    const int lane = t & 63;
    const int w    = t >> 6;
    const int qt   = w & 1;
    const int jt   = w >> 1;
    const int l31  = lane & 31;
    const int g    = lane >> 5;

    int bid = blockIdx.x;
    int half = 0;
    if (SPLIT) { half = bid >> 8; bid &= 255; }
    const int b      = bid >> 6;
    const int qb     = (bid & 63) * 64;
    const int jBegin = half * (HWSZ / 2);
    const int nt     = (SPLIT ? HWSZ / 2 : HWSZ) / 64;

    s16x8 qfrag[8];
    {
        const unsigned short* qp =
            Qbf + (((size_t)(b * HWSZ + qb + 32 * qt + l31)) << 7) + g * 8;
        #pragma unroll
        for (int fs = 0; fs < 8; ++fs)
            qfrag[fs] = *(const s16x8*)(qp + fs * 16);
    }

    f32x16 acc[4];
    #pragma unroll
    for (int ft = 0; ft < 4; ++ft)
        #pragma unroll
        for (int i = 0; i < 16; ++i) acc[ft][i] = 0.f;

    const unsigned short* Kbase = Kbf  + (((size_t)b * HWSZ) << 7);
    const unsigned short* Vbase = Vtbf + (((size_t)b) << 7) * HWSZ;

    const unsigned short* kSrc = Kbase + (size_t)(jBegin + (t >> 4)) * 128 + (t & 15) * 8;
    const unsigned short* vSrc = Vbase + (size_t)(t >> 3) * HWSZ + jBegin + (t & 7) * 8;
    const int kDst = (t >> 4) * KT_STR + (t & 15) * 8;
    const int vDst = (t >> 3) * VT_STR + (t & 7) * 8;

    {
        unsigned short* Kl = (unsigned short*)smem;
        unsigned short* Vl = (unsigned short*)(smem + KT_BYTES);
        #pragma unroll
        for (int i = 0; i < 4; ++i)
            *(s16x8*)(Kl + kDst + i * 16 * KT_STR) = *(const s16x8*)(kSrc + (size_t)i * 2048);
        #pragma unroll
        for (int i = 0; i < 4; ++i)
            *(s16x8*)(Vl + vDst + i * 32 * VT_STR) = *(const s16x8*)(vSrc + (size_t)i * 32 * HWSZ);
    }
    __syncthreads();

    int c = 0;
    for (int it = 0; it < nt; ++it) {
        const bool pre = (it + 1 < nt);
        s16x8 kr[4], vr[4];
        if (pre) {
            kSrc += 64 * 128;
            vSrc += 64;
            #pragma unroll
            for (int i = 0; i < 4; ++i)
                kr[i] = *(const s16x8*)(kSrc + (size_t)i * 2048);
            #pragma unroll
            for (int i = 0; i < 4; ++i)
                vr[i] = *(const s16x8*)(vSrc + (size_t)i * 32 * HWSZ);
        }

        const unsigned short* Kl = (const unsigned short*)(smem + c * BUF_BYTES);
        const unsigned short* Vl = (const unsigned short*)(smem + c * BUF_BYTES + KT_BYTES);

        f32x16 sa, sb;
        #pragma unroll
        for (int i = 0; i < 16; ++i) { sa[i] = 0.f; sb[i] = 0.f; }
        const unsigned short* Krow = Kl + (size_t)(32 * jt + l31) * KT_STR + g * 8;
        __builtin_amdgcn_s_setprio(1);
        #pragma unroll
        for (int fs = 0; fs < 4; ++fs) {
            sa = __builtin_amdgcn_mfma_f32_32x32x16_bf16(
                     *(const s16x8*)(Krow + fs * 16), qfrag[fs], sa, 0, 0, 0);
            sb = __builtin_amdgcn_mfma_f32_32x32x16_bf16(
                     *(const s16x8*)(Krow + (fs + 4) * 16), qfrag[fs + 4], sb, 0, 0, 0);
        }
        __builtin_amdgcn_s_setprio(0);

        unsigned W0[4], W1[4];
        #pragma unroll
        for (int rg = 0; rg < 4; ++rg) {
            float s0 = sa[4 * rg + 0] + sb[4 * rg + 0];
            float s1 = sa[4 * rg + 1] + sb[4 * rg + 1];
            float s2v = sa[4 * rg + 2] + sb[4 * rg + 2];
            float s3 = sa[4 * rg + 3] + sb[4 * rg + 3];
            float p0 = __builtin_amdgcn_rcpf(1.f + __builtin_amdgcn_exp2f(-s0));
            float p1 = __builtin_amdgcn_rcpf(1.f + __builtin_amdgcn_exp2f(-s1));
            float p2 = __builtin_amdgcn_rcpf(1.f + __builtin_amdgcn_exp2f(-s2v));
            float p3 = __builtin_amdgcn_rcpf(1.f + __builtin_amdgcn_exp2f(-s3));
            W0[rg] = cvt_pk_bf16(p0, p1);
            W1[rg] = cvt_pk_bf16(p2, p3);
        }

        #pragma unroll
        for (int s2 = 0; s2 < 2; ++s2) {
            unsigned a0 = W0[2 * s2], b0 = W0[2 * s2 + 1];
            unsigned a1 = W1[2 * s2], b1 = W1[2 * s2 + 1];
            asm("v_permlane32_swap_b32 %0, %1" : "+v"(a0), "+v"(b0));
            asm("v_permlane32_swap_b32 %0, %1" : "+v"(a1), "+v"(b1));
            u32x4 pw;
            pw[0] = a0; pw[1] = a1; pw[2] = b0; pw[3] = b1;
            s16x8 pf = __builtin_bit_cast(s16x8, pw);
            const int ks = 2 * jt + s2;
            __builtin_amdgcn_s_setprio(1);
            #pragma unroll
            for (int ft = 0; ft < 4; ++ft) {
                s16x8 vf = *(const s16x8*)(Vl + (size_t)(32 * ft + l31) * VT_STR + ks * 16 + g * 8);
                acc[ft] = __builtin_amdgcn_mfma_f32_32x32x16_bf16(pf, vf, acc[ft], 0, 0, 0);
            }
            __builtin_amdgcn_s_setprio(0);
        }

        if (pre) {
            unsigned short* Kd = (unsigned short*)(smem + (c ^ 1) * BUF_BYTES);
            unsigned short* Vd = (unsigned short*)(smem + (c ^ 1) * BUF_BYTES + KT_BYTES);
            #pragma unroll
            for (int i = 0; i < 4; ++i)
                *(s16x8*)(Kd + kDst + i * 16 * KT_STR) = kr[i];
            #pragma unroll
            for (int i = 0; i < 4; ++i)
                *(s16x8*)(Vd + vDst + i * 32 * VT_STR) = vr[i];
        }
        __syncthreads();
        c ^= 1;
    }

    float* red = (float*)smem;
    if (jt == 1) {
        #pragma unroll
        for (int ft = 0; ft < 4; ++ft)
        #pragma unroll
        for (int r = 0; r < 16; ++r) {
            int row = (r & 3) + 8 * (r >> 2) + 4 * g;
            red[qt * 4096 + row * 128 + 32 * ft + l31] = acc[ft][r];
        }
    }
    __syncthreads();
    if (jt == 0) {
        float* op = outp + (SPLIT ? (size_t)half * ((size_t)NBATCH * HWSZ * 128) : 0);
        #pragma unroll
        for (int ft = 0; ft < 4; ++ft)
        #pragma unroll
        for (int r = 0; r < 16; ++r) {
            int row = (r & 3) + 8 * (r >> 2) + 4 * g;
            float v = acc[ft][r] + red[qt * 4096 + row * 128 + 32 * ft + l31];
            int q = qb + 32 * qt + row;
            size_t o = (((size_t)(b * HWSZ + q)) << 7) + 32 * ft + l31;
            if (SPLIT) op[o] = v;
            else       op[o] = v + resid[o];
        }
    }
}

// ---------------- Kernel 3: partial reduce + residual ----------------
__global__ __launch_bounds__(256, 1) void reduce2_kernel(
    const float* __restrict__ p0, const float* __restrict__ p1, float* outp)
{
    int i = blockIdx.x * 256 + threadIdx.x;
    f32x4 a = ((const f32x4*)p0)[i];
    f32x4 b = ((const f32x4*)p1)[i];
    f32x4 c = ((f32x4*)outp)[i];
    ((f32x4*)outp)[i] = a + b + c;
}

template<int S>
__global__ __launch_bounds__(256, 1) void reduceN_kernel(
    const float* __restrict__ parts, float* __restrict__ outp)
{
    const size_t N4 = (size_t)NBATCH * HWSZ * 128 / 4;
    size_t i = (size_t)blockIdx.x * 256 + threadIdx.x;
    f32x4 s = ((f32x4*)outp)[i];          // xq residual
    #pragma unroll
    for (int k = 0; k < S; ++k)
        s += ((const f32x4*)parts)[i + (size_t)k * N4];
    ((f32x4*)outp)[i] = s;
}

extern "C" void kernel_launch(void* const* d_in, const int* in_sizes, int n_in,
                              void* d_out, int out_size, void* d_ws, size_t ws_size,
                              hipStream_t stream) {
    const float* x  = (const float*)d_in[0];
    const float* y  = (const float*)d_in[1];
    const float* W1 = (const float*)d_in[2];
    const float* b1 = (const float*)d_in[3];
    const float* W2 = (const float*)d_in[4];
    const float* b2 = (const float*)d_in[5];
    float* out = (float*)d_out;

    const size_t NELEM = (size_t)NBATCH * HWSZ * 128;   // 2,097,152
    unsigned short* xq_bf  = (unsigned short*)d_ws;
    unsigned short* yk_bf  = xq_bf + NELEM;
    unsigned short* ykT_bf = yk_bf + NELEM;
    float* part = (float*)(ykT_bf + NELEM);

    proj_kernel<<<(int)(NBATCH * HWSZ / 64), 256, 0, stream>>>(
        x, y, W1, b1, W2, b2, out, xq_bf, yk_bf, ykT_bf);

    if (ws_size >= NELEM * (6 + 24)) {               // 62.9 MB: QBLK=128, 6-split, 3 WG/CU
        attn128s6_kernel<<<768, 256, 0, stream>>>(xq_bf, yk_bf, ykT_bf, part);
        reduceN_kernel<6><<<(int)(NELEM / 1024), 256, 0, stream>>>(part, out);
    } else if (ws_size >= NELEM * (6 + 16)) {        // 46.1 MB: QBLK=128, 4-split
        attn128_kernel<<<512, 256, 0, stream>>>(xq_bf, yk_bf, ykT_bf, part);
        reduceN_kernel<4><<<(int)(NELEM / 1024), 256, 0, stream>>>(part, out);
    } else if (ws_size >= NELEM * (6 + 8)) {         // 29.4 MB: QBLK=64, 2-split
        attn_kernel<true><<<512, 256, 0, stream>>>(xq_bf, yk_bf, ykT_bf, out, part);
        reduce2_kernel<<<(int)(NELEM / 1024), 256, 0, stream>>>(part, part + NELEM, out);
    } else {
        attn_kernel<false><<<256, 256, 0, stream>>>(xq_bf, yk_bf, ykT_bf, out, out);
    }
}

// Round 10
// 67.758 us; speedup vs baseline: 1.4297x; 1.4297x over previous
//
#include <hip/hip_runtime.h>
#include <hip/hip_bf16.h>
#include <stdint.h>

typedef float f32x16 __attribute__((ext_vector_type(16)));
typedef float f32x4  __attribute__((ext_vector_type(4)));
typedef short s16x8  __attribute__((ext_vector_type(8)));
typedef unsigned int u32x4 __attribute__((ext_vector_type(4)));

#define HWSZ   4096
#define NBATCH 4
#define LOG2E  1.44269504088896340736f

__device__ __forceinline__ unsigned short f2bf(float f) {
    unsigned u = __builtin_bit_cast(unsigned, f);
    u += 0x7FFFu + ((u >> 16) & 1u);          // RTNE
    return (unsigned short)(u >> 16);
}
__device__ __forceinline__ unsigned cvt_pk_bf16(float lo, float hi) {
    __hip_bfloat162 h = __float22bfloat162_rn(make_float2(lo, hi));
    return *reinterpret_cast<unsigned*>(&h);   // v_cvt_pk_bf16_f32
}

// ---------------- Kernel 1: MFMA projections ----------------
// xq = x@W1 + b1 -> d_out (f32 residual) + xq_bf (bf16, PRE-SCALED by log2e: K-only)
// yk = y@W2 + b2 -> yk_bf (bf16) + ykT_bf (bf16 transposed)
__global__ __launch_bounds__(256, 1) void proj_kernel(
    const float* __restrict__ x, const float* __restrict__ y,
    const float* __restrict__ W1, const float* __restrict__ b1,
    const float* __restrict__ W2, const float* __restrict__ b2,
    float* __restrict__ xq_f32,
    unsigned short* __restrict__ xq_bf,
    unsigned short* __restrict__ yk_bf,
    unsigned short* __restrict__ ykT_bf)
{
    __shared__ unsigned short Xlds[64][136];
    __shared__ unsigned short Ylds[64][136];
    __shared__ unsigned short Tlds[128][72];

    const int t    = threadIdx.x;
    const int lane = t & 63;
    const int w    = t >> 6;
    const int l31  = lane & 31;
    const int g    = lane >> 5;
    const int r0   = blockIdx.x * 64;
    const int b    = r0 >> 12;
    const int j0   = r0 & (HWSZ - 1);

    #pragma unroll
    for (int i = 0; i < 8; ++i) {
        int li = t + 256 * i;
        int row = li >> 5, c = (li & 31) * 4;
        float4 vx = *(const float4*)(x + (size_t)(r0 + row) * 128 + c);
        float4 vy = *(const float4*)(y + (size_t)(r0 + row) * 128 + c);
        *(uint2*)&Xlds[row][c] = make_uint2(cvt_pk_bf16(vx.x, vx.y), cvt_pk_bf16(vx.z, vx.w));
        *(uint2*)&Ylds[row][c] = make_uint2(cvt_pk_bf16(vy.x, vy.y), cvt_pk_bf16(vy.z, vy.w));
    }
    __syncthreads();

    const int m  = w >> 1;
    const int fh = w & 1;
    const float* Wm = m ? W2 : W1;
    const float* bm = m ? b2 : b1;
    const unsigned short* A0 = m ? &Ylds[0][0] : &Xlds[0][0];

    f32x16 acc[2][2];
    #pragma unroll
    for (int i = 0; i < 16; ++i) {
        acc[0][0][i] = 0.f; acc[0][1][i] = 0.f;
        acc[1][0][i] = 0.f; acc[1][1][i] = 0.f;
    }

    #pragma unroll
    for (int ks = 0; ks < 8; ++ks) {
        s16x8 bfr[2];
        #pragma unroll
        for (int ft = 0; ft < 2; ++ft) {
            const float* wp = Wm + (size_t)(ks * 16 + g * 8) * 128 + fh * 64 + ft * 32 + l31;
            #pragma unroll
            for (int i = 0; i < 8; ++i)
                bfr[ft][i] = (short)f2bf(wp[(size_t)i * 128]);
        }
        #pragma unroll
        for (int rt = 0; rt < 2; ++rt) {
            s16x8 af = *(const s16x8*)(A0 + (size_t)(rt * 32 + l31) * 136 + ks * 16 + g * 8);
            acc[rt][0] = __builtin_amdgcn_mfma_f32_32x32x16_bf16(af, bfr[0], acc[rt][0], 0, 0, 0);
            acc[rt][1] = __builtin_amdgcn_mfma_f32_32x32x16_bf16(af, bfr[1], acc[rt][1], 0, 0, 0);
        }
    }

    const float bias_v[2] = { bm[fh * 64 + l31], bm[fh * 64 + 32 + l31] };

    if (m == 0) {
        #pragma unroll
        for (int rt = 0; rt < 2; ++rt)
        #pragma unroll
        for (int ft = 0; ft < 2; ++ft) {
            int f = fh * 64 + ft * 32 + l31;
            #pragma unroll
            for (int r = 0; r < 16; ++r) {
                int row = rt * 32 + (r & 3) + 8 * (r >> 2) + 4 * g;
                float v = acc[rt][ft][r] + bias_v[ft];
                size_t o = (size_t)(r0 + row) * 128 + f;
                xq_f32[o] = v;
                xq_bf[o]  = f2bf(v * LOG2E);      // K pre-scaled for exp2 sigmoid
            }
        }
    } else {
        #pragma unroll
        for (int rt = 0; rt < 2; ++rt)
        #pragma unroll
        for (int ft = 0; ft < 2; ++ft) {
            int f = fh * 64 + ft * 32 + l31;
            #pragma unroll
            for (int rg = 0; rg < 4; ++rg) {
                float p0 = acc[rt][ft][4 * rg + 0] + bias_v[ft];
                float p1 = acc[rt][ft][4 * rg + 1] + bias_v[ft];
                float p2 = acc[rt][ft][4 * rg + 2] + bias_v[ft];
                float p3 = acc[rt][ft][4 * rg + 3] + bias_v[ft];
                int jb = rt * 32 + 8 * rg + 4 * g;
                *(uint2*)&Tlds[f][jb] = make_uint2(cvt_pk_bf16(p0, p1), cvt_pk_bf16(p2, p3));
                size_t o = (size_t)(r0 + jb) * 128 + f;
                yk_bf[o]       = f2bf(p0);
                yk_bf[o + 128] = f2bf(p1);
                yk_bf[o + 256] = f2bf(p2);
                yk_bf[o + 384] = f2bf(p3);
            }
        }
    }
    __syncthreads();

    {
        int f  = t >> 1;
        int jh = (t & 1) * 32;
        unsigned short* dst = ykT_bf + ((size_t)(b * 128 + f)) * HWSZ + j0 + jh;
        #pragma unroll
        for (int c = 0; c < 4; ++c)
            *(s16x8*)(dst + c * 8) = *(const s16x8*)&Tlds[f][jh + c * 8];
    }
}

// ---------------- shared attention LDS geometry ----------------
#define KT_STR   136
#define VT_STR   72
#define KT_BYTES (64 * KT_STR * 2)     // 17408
#define VT_BYTES (128 * VT_STR * 2)    // 18432
#define BUF_BYTES (KT_BYTES + VT_BYTES)

// ---------------- Kernel 2a: QBLK=128, 4-split, deep-ILP inner loop ----------
// Per staged 64-j tile: (1) all 16 K-frags hoisted, (2) QK as 4 independent
// MFMA chains (no dep stalls), (3) staging loads issued mid-iter (off the QK
// register peak; ~700cy before write-late), (4) one combined 32-value sigmoid,
// (5) 16 PV MFMA. Peak regs ~236 <= 256 ((256,2)) -> no spill.
__global__ __launch_bounds__(256, 2) void attn128_kernel(
    const unsigned short* __restrict__ Kbf,   // xq_bf (log2e-scaled) [b][j][128]
    const unsigned short* __restrict__ Qbf,   // yk_bf  [b][q][128]
    const unsigned short* __restrict__ Vtbf,  // ykT_bf [b][128][4096]
    float* __restrict__ outp)                 // partials base (4 x NELEM)
{
    __shared__ __align__(16) char smem[2 * BUF_BYTES];

    const int t    = threadIdx.x;
    const int lane = t & 63;
    const int qt   = t >> 6;
    const int l31  = lane & 31;
    const int g    = lane >> 5;

    const int split  = blockIdx.x >> 7;       // 0..3
    const int r      = blockIdx.x & 127;
    const int b      = r >> 5;
    const int qb     = (r & 31) * 128;
    const int jBegin = split * (HWSZ / 4);
    const int nt     = (HWSZ / 4) / 64;       // 16

    s16x8 qfrag[8];
    {
        const unsigned short* qp =
            Qbf + (((size_t)(b * HWSZ + qb + 32 * qt + l31)) << 7) + g * 8;
        #pragma unroll
        for (int fs = 0; fs < 8; ++fs)
            qfrag[fs] = *(const s16x8*)(qp + fs * 16);
    }

    f32x16 acc[4];
    #pragma unroll
    for (int ft = 0; ft < 4; ++ft)
        #pragma unroll
        for (int i = 0; i < 16; ++i) acc[ft][i] = 0.f;

    const unsigned short* Kbase = Kbf  + (((size_t)b * HWSZ) << 7);
    const unsigned short* Vbase = Vtbf + (((size_t)b) << 7) * HWSZ;

    const unsigned short* kSrc = Kbase + (size_t)(jBegin + (t >> 4)) * 128 + (t & 15) * 8;
    const unsigned short* vSrc = Vbase + (size_t)(t >> 3) * HWSZ + jBegin + (t & 7) * 8;
    const int kDst = (t >> 4) * KT_STR + (t & 15) * 8;
    const int vDst = (t >> 3) * VT_STR + (t & 7) * 8;

    {   // prologue: stage tile 0 into buf 0
        unsigned short* Kl = (unsigned short*)smem;
        unsigned short* Vl = (unsigned short*)(smem + KT_BYTES);
        #pragma unroll
        for (int i = 0; i < 4; ++i)
            *(s16x8*)(Kl + kDst + i * 16 * KT_STR) = *(const s16x8*)(kSrc + (size_t)i * 2048);
        #pragma unroll
        for (int i = 0; i < 4; ++i)
            *(s16x8*)(Vl + vDst + i * 32 * VT_STR) = *(const s16x8*)(vSrc + (size_t)i * 32 * HWSZ);
    }
    __syncthreads();

    int c = 0;
    for (int it = 0; it < nt; ++it) {
        const bool pre = (it + 1 < nt);
        const unsigned short* Kl = (const unsigned short*)(smem + c * BUF_BYTES);
        const unsigned short* Vl = (const unsigned short*)(smem + c * BUF_BYTES + KT_BYTES);

        // ---- 1) hoist all 16 K-frags (both jt subtiles) ----
        s16x8 kf[16];
        #pragma unroll
        for (int jt = 0; jt < 2; ++jt) {
            const unsigned short* Krow = Kl + (size_t)(32 * jt + l31) * KT_STR + g * 8;
            #pragma unroll
            for (int fs = 0; fs < 8; ++fs)
                kf[jt * 8 + fs] = *(const s16x8*)(Krow + fs * 16);
        }

        // ---- 2) QK: 4 independent chains, zero dep-stall ----
        f32x16 s0a, s0b, s1a, s1b;
        #pragma unroll
        for (int i = 0; i < 16; ++i) { s0a[i] = 0.f; s0b[i] = 0.f; s1a[i] = 0.f; s1b[i] = 0.f; }
        __builtin_amdgcn_s_setprio(1);
        #pragma unroll
        for (int fs = 0; fs < 4; ++fs) {
            s0a = __builtin_amdgcn_mfma_f32_32x32x16_bf16(kf[fs],         qfrag[fs],     s0a, 0, 0, 0);
            s0b = __builtin_amdgcn_mfma_f32_32x32x16_bf16(kf[fs + 4],     qfrag[fs + 4], s0b, 0, 0, 0);
            s1a = __builtin_amdgcn_mfma_f32_32x32x16_bf16(kf[8 + fs],     qfrag[fs],     s1a, 0, 0, 0);
            s1b = __builtin_amdgcn_mfma_f32_32x32x16_bf16(kf[8 + fs + 4], qfrag[fs + 4], s1b, 0, 0, 0);
        }
        __builtin_amdgcn_s_setprio(0);

        // ---- 3) issue-early staging loads (mid-iter: off the QK reg peak,
        //         ~SM+PV cycles before the write-late drains them) ----
        s16x8 kr[4], vr[4];
        if (pre) {
            kSrc += 64 * 128;
            vSrc += 64;
            #pragma unroll
            for (int i = 0; i < 4; ++i)
                kr[i] = *(const s16x8*)(kSrc + (size_t)i * 2048);
            #pragma unroll
            for (int i = 0; i < 4; ++i)
                vr[i] = *(const s16x8*)(vSrc + (size_t)i * 32 * HWSZ);
        }

        // ---- 4) sigmoid, both jt at once (32 independent values) ----
        unsigned W0[2][4], W1[2][4];
        {
            f32x16 sv0, sv1;
            #pragma unroll
            for (int i = 0; i < 16; ++i) { sv0[i] = s0a[i] + s0b[i]; sv1[i] = s1a[i] + s1b[i]; }
            #pragma unroll
            for (int rg = 0; rg < 4; ++rg) {
                float a0 = __builtin_amdgcn_rcpf(1.f + __builtin_amdgcn_exp2f(-sv0[4 * rg + 0]));
                float a1 = __builtin_amdgcn_rcpf(1.f + __builtin_amdgcn_exp2f(-sv0[4 * rg + 1]));
                float a2 = __builtin_amdgcn_rcpf(1.f + __builtin_amdgcn_exp2f(-sv0[4 * rg + 2]));
                float a3 = __builtin_amdgcn_rcpf(1.f + __builtin_amdgcn_exp2f(-sv0[4 * rg + 3]));
                float b0 = __builtin_amdgcn_rcpf(1.f + __builtin_amdgcn_exp2f(-sv1[4 * rg + 0]));
                float b1 = __builtin_amdgcn_rcpf(1.f + __builtin_amdgcn_exp2f(-sv1[4 * rg + 1]));
                float b2 = __builtin_amdgcn_rcpf(1.f + __builtin_amdgcn_exp2f(-sv1[4 * rg + 2]));
                float b3 = __builtin_amdgcn_rcpf(1.f + __builtin_amdgcn_exp2f(-sv1[4 * rg + 3]));
                W0[0][rg] = cvt_pk_bf16(a0, a1);
                W1[0][rg] = cvt_pk_bf16(a2, a3);
                W0[1][rg] = cvt_pk_bf16(b0, b1);
                W1[1][rg] = cvt_pk_bf16(b2, b3);
            }
        }

        // ---- 5) PV: 16 MFMA (4 ft chains), A-frags via permlane32_swap ----
        __builtin_amdgcn_s_setprio(1);
        #pragma unroll
        for (int jt = 0; jt < 2; ++jt)
        #pragma unroll
        for (int s2 = 0; s2 < 2; ++s2) {
            unsigned a0 = W0[jt][2 * s2], b0 = W0[jt][2 * s2 + 1];
            unsigned a1 = W1[jt][2 * s2], b1 = W1[jt][2 * s2 + 1];
            asm("v_permlane32_swap_b32 %0, %1" : "+v"(a0), "+v"(b0));
            asm("v_permlane32_swap_b32 %0, %1" : "+v"(a1), "+v"(b1));
            u32x4 pw;
            pw[0] = a0; pw[1] = a1; pw[2] = b0; pw[3] = b1;
            s16x8 pf = __builtin_bit_cast(s16x8, pw);
            const int ks = 2 * jt + s2;
            #pragma unroll
            for (int ft = 0; ft < 4; ++ft) {
                s16x8 vf = *(const s16x8*)(Vl + (size_t)(32 * ft + l31) * VT_STR + ks * 16 + g * 8);
                acc[ft] = __builtin_amdgcn_mfma_f32_32x32x16_bf16(pf, vf, acc[ft], 0, 0, 0);
            }
        }
        __builtin_amdgcn_s_setprio(0);

        // ---- 6) write-late into other buffer ----
        if (pre) {
            unsigned short* Kd = (unsigned short*)(smem + (c ^ 1) * BUF_BYTES);
            unsigned short* Vd = (unsigned short*)(smem + (c ^ 1) * BUF_BYTES + KT_BYTES);
            #pragma unroll
            for (int i = 0; i < 4; ++i)
                *(s16x8*)(Kd + kDst + i * 16 * KT_STR) = kr[i];
            #pragma unroll
            for (int i = 0; i < 4; ++i)
                *(s16x8*)(Vd + vDst + i * 32 * VT_STR) = vr[i];
        }
        __syncthreads();
        c ^= 1;
    }

    // ---- epilogue: direct store of wave-private 32q x 128f partial ----
    float* op = outp + (size_t)split * ((size_t)NBATCH * HWSZ * 128);
    #pragma unroll
    for (int ft = 0; ft < 4; ++ft)
    #pragma unroll
    for (int r2 = 0; r2 < 16; ++r2) {
        int row = (r2 & 3) + 8 * (r2 >> 2) + 4 * g;
        int q = qb + 32 * qt + row;
        size_t o = (((size_t)(b * HWSZ + q)) << 7) + 32 * ft + l31;
        op[o] = acc[ft][r2];
    }
}

// ---------------- Kernel 2b: QBLK=64 fallback (2-split / no-split) ----------------
template<bool SPLIT>
__global__ __launch_bounds__(256, 2) void attn_kernel(
    const unsigned short* __restrict__ Kbf,
    const unsigned short* __restrict__ Qbf,
    const unsigned short* __restrict__ Vtbf,
    const float* __restrict__ resid,
    float* __restrict__ outp)
{
    __shared__ __align__(16) char smem[2 * BUF_BYTES];

    const int t    = threadIdx.x;
    const int lane = t & 63;
    const int w    = t >> 6;
    const int qt   = w & 1;
    const int jt   = w >> 1;
    const int l31  = lane & 31;
    const int g    = lane >> 5;

    int bid = blockIdx.x;
    int half = 0;
    if (SPLIT) { half = bid >> 8; bid &= 255; }
    const int b      = bid >> 6;
    const int qb     = (bid & 63) * 64;
    const int jBegin = half * (HWSZ / 2);
    const int nt     = (SPLIT ? HWSZ / 2 : HWSZ) / 64;

    s16x8 qfrag[8];
    {
        const unsigned short* qp =
            Qbf + (((size_t)(b * HWSZ + qb + 32 * qt + l31)) << 7) + g * 8;
        #pragma unroll
        for (int fs = 0; fs < 8; ++fs)
            qfrag[fs] = *(const s16x8*)(qp + fs * 16);
    }

    f32x16 acc[4];
    #pragma unroll
    for (int ft = 0; ft < 4; ++ft)
        #pragma unroll
        for (int i = 0; i < 16; ++i) acc[ft][i] = 0.f;

    const unsigned short* Kbase = Kbf  + (((size_t)b * HWSZ) << 7);
    const unsigned short* Vbase = Vtbf + (((size_t)b) << 7) * HWSZ;

    const unsigned short* kSrc = Kbase + (size_t)(jBegin + (t >> 4)) * 128 + (t & 15) * 8;
    const unsigned short* vSrc = Vbase + (size_t)(t >> 3) * HWSZ + jBegin + (t & 7) * 8;
    const int kDst = (t >> 4) * KT_STR + (t & 15) * 8;
    const int vDst = (t >> 3) * VT_STR + (t & 7) * 8;

    {
        unsigned short* Kl = (unsigned short*)smem;
        unsigned short* Vl = (unsigned short*)(smem + KT_BYTES);
        #pragma unroll
        for (int i = 0; i < 4; ++i)
            *(s16x8*)(Kl + kDst + i * 16 * KT_STR) = *(const s16x8*)(kSrc + (size_t)i * 2048);
        #pragma unroll
        for (int i = 0; i < 4; ++i)
            *(s16x8*)(Vl + vDst + i * 32 * VT_STR) = *(const s16x8*)(vSrc + (size_t)i * 32 * HWSZ);
    }
    __syncthreads();

    int c = 0;
    for (int it = 0; it < nt; ++it) {
        const bool pre = (it + 1 < nt);
        s16x8 kr[4], vr[4];
        if (pre) {
            kSrc += 64 * 128;
            vSrc += 64;
            #pragma unroll
            for (int i = 0; i < 4; ++i)
                kr[i] = *(const s16x8*)(kSrc + (size_t)i * 2048);
            #pragma unroll
            for (int i = 0; i < 4; ++i)
                vr[i] = *(const s16x8*)(vSrc + (size_t)i * 32 * HWSZ);
        }

        const unsigned short* Kl = (const unsigned short*)(smem + c * BUF_BYTES);
        const unsigned short* Vl = (const unsigned short*)(smem + c * BUF_BYTES + KT_BYTES);

        f32x16 sa, sb;
        #pragma unroll
        for (int i = 0; i < 16; ++i) { sa[i] = 0.f; sb[i] = 0.f; }
        const unsigned short* Krow = Kl + (size_t)(32 * jt + l31) * KT_STR + g * 8;
        __builtin_amdgcn_s_setprio(1);
        #pragma unroll
        for (int fs = 0; fs < 4; ++fs) {
            sa = __builtin_amdgcn_mfma_f32_32x32x16_bf16(
                     *(const s16x8*)(Krow + fs * 16), qfrag[fs], sa, 0, 0, 0);
            sb = __builtin_amdgcn_mfma_f32_32x32x16_bf16(
                     *(const s16x8*)(Krow + (fs + 4) * 16), qfrag[fs + 4], sb, 0, 0, 0);
        }
        __builtin_amdgcn_s_setprio(0);

        unsigned W0[4], W1[4];
        #pragma unroll
        for (int rg = 0; rg < 4; ++rg) {
            float s0 = sa[4 * rg + 0] + sb[4 * rg + 0];
            float s1 = sa[4 * rg + 1] + sb[4 * rg + 1];
            float s2v = sa[4 * rg + 2] + sb[4 * rg + 2];
            float s3 = sa[4 * rg + 3] + sb[4 * rg + 3];
            float p0 = __builtin_amdgcn_rcpf(1.f + __builtin_amdgcn_exp2f(-s0));
            float p1 = __builtin_amdgcn_rcpf(1.f + __builtin_amdgcn_exp2f(-s1));
            float p2 = __builtin_amdgcn_rcpf(1.f + __builtin_amdgcn_exp2f(-s2v));
            float p3 = __builtin_amdgcn_rcpf(1.f + __builtin_amdgcn_exp2f(-s3));
            W0[rg] = cvt_pk_bf16(p0, p1);
            W1[rg] = cvt_pk_bf16(p2, p3);
        }

        #pragma unroll
        for (int s2 = 0; s2 < 2; ++s2) {
            unsigned a0 = W0[2 * s2], b0 = W0[2 * s2 + 1];
            unsigned a1 = W1[2 * s2], b1 = W1[2 * s2 + 1];
            asm("v_permlane32_swap_b32 %0, %1" : "+v"(a0), "+v"(b0));
            asm("v_permlane32_swap_b32 %0, %1" : "+v"(a1), "+v"(b1));
            u32x4 pw;
            pw[0] = a0; pw[1] = a1; pw[2] = b0; pw[3] = b1;
            s16x8 pf = __builtin_bit_cast(s16x8, pw);
            const int ks = 2 * jt + s2;
            __builtin_amdgcn_s_setprio(1);
            #pragma unroll
            for (int ft = 0; ft < 4; ++ft) {
                s16x8 vf = *(const s16x8*)(Vl + (size_t)(32 * ft + l31) * VT_STR + ks * 16 + g * 8);
                acc[ft] = __builtin_amdgcn_mfma_f32_32x32x16_bf16(pf, vf, acc[ft], 0, 0, 0);
            }
            __builtin_amdgcn_s_setprio(0);
        }

        if (pre) {
            unsigned short* Kd = (unsigned short*)(smem + (c ^ 1) * BUF_BYTES);
            unsigned short* Vd = (unsigned short*)(smem + (c ^ 1) * BUF_BYTES + KT_BYTES);
            #pragma unroll
            for (int i = 0; i < 4; ++i)
                *(s16x8*)(Kd + kDst + i * 16 * KT_STR) = kr[i];
            #pragma unroll
            for (int i = 0; i < 4; ++i)
                *(s16x8*)(Vd + vDst + i * 32 * VT_STR) = vr[i];
        }
        __syncthreads();
        c ^= 1;
    }

    float* red = (float*)smem;
    if (jt == 1) {
        #pragma unroll
        for (int ft = 0; ft < 4; ++ft)
        #pragma unroll
        for (int r = 0; r < 16; ++r) {
            int row = (r & 3) + 8 * (r >> 2) + 4 * g;
            red[qt * 4096 + row * 128 + 32 * ft + l31] = acc[ft][r];
        }
    }
    __syncthreads();
    if (jt == 0) {
        float* op = outp + (SPLIT ? (size_t)half * ((size_t)NBATCH * HWSZ * 128) : 0);
        #pragma unroll
        for (int ft = 0; ft < 4; ++ft)
        #pragma unroll
        for (int r = 0; r < 16; ++r) {
            int row = (r & 3) + 8 * (r >> 2) + 4 * g;
            float v = acc[ft][r] + red[qt * 4096 + row * 128 + 32 * ft + l31];
            int q = qb + 32 * qt + row;
            size_t o = (((size_t)(b * HWSZ + q)) << 7) + 32 * ft + l31;
            if (SPLIT) op[o] = v;
            else       op[o] = v + resid[o];
        }
    }
}

// ---------------- Kernel 3: partial reduce + residual ----------------
__global__ __launch_bounds__(256, 1) void reduce2_kernel(
    const float* __restrict__ p0, const float* __restrict__ p1, float* outp)
{
    int i = blockIdx.x * 256 + threadIdx.x;
    f32x4 a = ((const f32x4*)p0)[i];
    f32x4 b = ((const f32x4*)p1)[i];
    f32x4 c = ((f32x4*)outp)[i];
    ((f32x4*)outp)[i] = a + b + c;
}

template<int S>
__global__ __launch_bounds__(256, 1) void reduceN_kernel(
    const float* __restrict__ parts, float* __restrict__ outp)
{
    const size_t N4 = (size_t)NBATCH * HWSZ * 128 / 4;
    size_t i = (size_t)blockIdx.x * 256 + threadIdx.x;
    f32x4 s = ((f32x4*)outp)[i];          // xq residual
    #pragma unroll
    for (int k = 0; k < S; ++k)
        s += ((const f32x4*)parts)[i + (size_t)k * N4];
    ((f32x4*)outp)[i] = s;
}

extern "C" void kernel_launch(void* const* d_in, const int* in_sizes, int n_in,
                              void* d_out, int out_size, void* d_ws, size_t ws_size,
                              hipStream_t stream) {
    const float* x  = (const float*)d_in[0];
    const float* y  = (const float*)d_in[1];
    const float* W1 = (const float*)d_in[2];
    const float* b1 = (const float*)d_in[3];
    const float* W2 = (const float*)d_in[4];
    const float* b2 = (const float*)d_in[5];
    float* out = (float*)d_out;

    const size_t NELEM = (size_t)NBATCH * HWSZ * 128;   // 2,097,152
    unsigned short* xq_bf  = (unsigned short*)d_ws;
    unsigned short* yk_bf  = xq_bf + NELEM;
    unsigned short* ykT_bf = yk_bf + NELEM;
    float* part = (float*)(ykT_bf + NELEM);

    proj_kernel<<<(int)(NBATCH * HWSZ / 64), 256, 0, stream>>>(
        x, y, W1, b1, W2, b2, out, xq_bf, yk_bf, ykT_bf);

    if (ws_size >= NELEM * (6 + 16)) {               // 46.1 MB: QBLK=128, 4-split
        attn128_kernel<<<512, 256, 0, stream>>>(xq_bf, yk_bf, ykT_bf, part);
        reduceN_kernel<4><<<(int)(NELEM / 1024), 256, 0, stream>>>(part, out);
    } else if (ws_size >= NELEM * (6 + 8)) {         // 29.4 MB: QBLK=64, 2-split
        attn_kernel<true><<<512, 256, 0, stream>>>(xq_bf, yk_bf, ykT_bf, out, part);
        reduce2_kernel<<<(int)(NELEM / 1024), 256, 0, stream>>>(part, part + NELEM, out);
    } else {
        attn_kernel<false><<<256, 256, 0, stream>>>(xq_bf, yk_bf, ykT_bf, out, out);
    }
}

// Round 11
// 65.836 us; speedup vs baseline: 1.4714x; 1.0292x over previous
//
#include <hip/hip_runtime.h>
#include <hip/hip_bf16.h>
#include <stdint.h>

typedef float f32x16 __attribute__((ext_vector_type(16)));
typedef float f32x4  __attribute__((ext_vector_type(4)));
typedef short s16x8  __attribute__((ext_vector_type(8)));
typedef unsigned int u32x4 __attribute__((ext_vector_type(4)));

#define HWSZ   4096
#define NBATCH 4
#define LOG2E  1.44269504088896340736f

__device__ __forceinline__ unsigned short f2bf(float f) {
    unsigned u = __builtin_bit_cast(unsigned, f);
    u += 0x7FFFu + ((u >> 16) & 1u);          // RTNE
    return (unsigned short)(u >> 16);
}
__device__ __forceinline__ unsigned cvt_pk_bf16(float lo, float hi) {
    __hip_bfloat162 h = __float22bfloat162_rn(make_float2(lo, hi));
    return *reinterpret_cast<unsigned*>(&h);   // v_cvt_pk_bf16_f32
}
__device__ __forceinline__ float sigm2(float s) {   // rcp(1+exp2(-s)); K pre-scaled
    return __builtin_amdgcn_rcpf(1.f + __builtin_amdgcn_exp2f(-s));
}

// ---------------- Kernel 1: MFMA projections ----------------
// xq = x@W1 + b1 -> d_out (f32 residual) + xq_bf (bf16, PRE-SCALED by log2e: K-only)
// yk = y@W2 + b2 -> yk_bf (bf16) + ykT_bf (bf16 transposed)
__global__ __launch_bounds__(256, 1) void proj_kernel(
    const float* __restrict__ x, const float* __restrict__ y,
    const float* __restrict__ W1, const float* __restrict__ b1,
    const float* __restrict__ W2, const float* __restrict__ b2,
    float* __restrict__ xq_f32,
    unsigned short* __restrict__ xq_bf,
    unsigned short* __restrict__ yk_bf,
    unsigned short* __restrict__ ykT_bf)
{
    __shared__ unsigned short Xlds[64][136];
    __shared__ unsigned short Ylds[64][136];
    __shared__ unsigned short Tlds[128][72];

    const int t    = threadIdx.x;
    const int lane = t & 63;
    const int w    = t >> 6;
    const int l31  = lane & 31;
    const int g    = lane >> 5;
    const int r0   = blockIdx.x * 64;
    const int b    = r0 >> 12;
    const int j0   = r0 & (HWSZ - 1);

    #pragma unroll
    for (int i = 0; i < 8; ++i) {
        int li = t + 256 * i;
        int row = li >> 5, c = (li & 31) * 4;
        float4 vx = *(const float4*)(x + (size_t)(r0 + row) * 128 + c);
        float4 vy = *(const float4*)(y + (size_t)(r0 + row) * 128 + c);
        *(uint2*)&Xlds[row][c] = make_uint2(cvt_pk_bf16(vx.x, vx.y), cvt_pk_bf16(vx.z, vx.w));
        *(uint2*)&Ylds[row][c] = make_uint2(cvt_pk_bf16(vy.x, vy.y), cvt_pk_bf16(vy.z, vy.w));
    }
    __syncthreads();

    const int m  = w >> 1;
    const int fh = w & 1;
    const float* Wm = m ? W2 : W1;
    const float* bm = m ? b2 : b1;
    const unsigned short* A0 = m ? &Ylds[0][0] : &Xlds[0][0];

    f32x16 acc[2][2];
    #pragma unroll
    for (int i = 0; i < 16; ++i) {
        acc[0][0][i] = 0.f; acc[0][1][i] = 0.f;
        acc[1][0][i] = 0.f; acc[1][1][i] = 0.f;
    }

    #pragma unroll
    for (int ks = 0; ks < 8; ++ks) {
        s16x8 bfr[2];
        #pragma unroll
        for (int ft = 0; ft < 2; ++ft) {
            const float* wp = Wm + (size_t)(ks * 16 + g * 8) * 128 + fh * 64 + ft * 32 + l31;
            #pragma unroll
            for (int i = 0; i < 8; ++i)
                bfr[ft][i] = (short)f2bf(wp[(size_t)i * 128]);
        }
        #pragma unroll
        for (int rt = 0; rt < 2; ++rt) {
            s16x8 af = *(const s16x8*)(A0 + (size_t)(rt * 32 + l31) * 136 + ks * 16 + g * 8);
            acc[rt][0] = __builtin_amdgcn_mfma_f32_32x32x16_bf16(af, bfr[0], acc[rt][0], 0, 0, 0);
            acc[rt][1] = __builtin_amdgcn_mfma_f32_32x32x16_bf16(af, bfr[1], acc[rt][1], 0, 0, 0);
        }
    }

    const float bias_v[2] = { bm[fh * 64 + l31], bm[fh * 64 + 32 + l31] };

    if (m == 0) {
        #pragma unroll
        for (int rt = 0; rt < 2; ++rt)
        #pragma unroll
        for (int ft = 0; ft < 2; ++ft) {
            int f = fh * 64 + ft * 32 + l31;
            #pragma unroll
            for (int r = 0; r < 16; ++r) {
                int row = rt * 32 + (r & 3) + 8 * (r >> 2) + 4 * g;
                float v = acc[rt][ft][r] + bias_v[ft];
                size_t o = (size_t)(r0 + row) * 128 + f;
                xq_f32[o] = v;
                xq_bf[o]  = f2bf(v * LOG2E);      // K pre-scaled for exp2 sigmoid
            }
        }
    } else {
        #pragma unroll
        for (int rt = 0; rt < 2; ++rt)
        #pragma unroll
        for (int ft = 0; ft < 2; ++ft) {
            int f = fh * 64 + ft * 32 + l31;
            #pragma unroll
            for (int rg = 0; rg < 4; ++rg) {
                float p0 = acc[rt][ft][4 * rg + 0] + bias_v[ft];
                float p1 = acc[rt][ft][4 * rg + 1] + bias_v[ft];
                float p2 = acc[rt][ft][4 * rg + 2] + bias_v[ft];
                float p3 = acc[rt][ft][4 * rg + 3] + bias_v[ft];
                int jb = rt * 32 + 8 * rg + 4 * g;
                *(uint2*)&Tlds[f][jb] = make_uint2(cvt_pk_bf16(p0, p1), cvt_pk_bf16(p2, p3));
                size_t o = (size_t)(r0 + jb) * 128 + f;
                yk_bf[o]       = f2bf(p0);
                yk_bf[o + 128] = f2bf(p1);
                yk_bf[o + 256] = f2bf(p2);
                yk_bf[o + 384] = f2bf(p3);
            }
        }
    }
    __syncthreads();

    {
        int f  = t >> 1;
        int jh = (t & 1) * 32;
        unsigned short* dst = ykT_bf + ((size_t)(b * 128 + f)) * HWSZ + j0 + jh;
        #pragma unroll
        for (int c = 0; c < 4; ++c)
            *(s16x8*)(dst + c * 8) = *(const s16x8*)&Tlds[f][jh + c * 8];
    }
}

// ---------------- shared attention LDS geometry ----------------
#define KT_STR   136
#define VT_STR   72
#define KT_BYTES (64 * KT_STR * 2)     // 17408
#define VT_BYTES (128 * VT_STR * 2)    // 18432
#define BUF_BYTES (KT_BYTES + VT_BYTES)

// ---------------- Kernel 2a: QBLK=128, 4-split, phase-interleaved ----------
// Per staged 64-j tile, 4 overlapped stages:
//   QK0 -> {QK1 || sigmoid0} -> {PV0 || sigmoid1} -> PV1
// Each sigmoid half (16 TRANS pairs) sits beside an independent 8-MFMA cluster
// so the wave issues VALU/TRANS into the MFMA shadow. Staging loads mid-iter.
__global__ __launch_bounds__(256, 2) void attn128_kernel(
    const unsigned short* __restrict__ Kbf,   // xq_bf (log2e-scaled) [b][j][128]
    const unsigned short* __restrict__ Qbf,   // yk_bf  [b][q][128]
    const unsigned short* __restrict__ Vtbf,  // ykT_bf [b][128][4096]
    float* __restrict__ outp)                 // partials base (4 x NELEM)
{
    __shared__ __align__(16) char smem[2 * BUF_BYTES];

    const int t    = threadIdx.x;
    const int lane = t & 63;
    const int qt   = t >> 6;
    const int l31  = lane & 31;
    const int g    = lane >> 5;

    const int split  = blockIdx.x >> 7;       // 0..3
    const int r      = blockIdx.x & 127;
    const int b      = r >> 5;
    const int qb     = (r & 31) * 128;
    const int jBegin = split * (HWSZ / 4);
    const int nt     = (HWSZ / 4) / 64;       // 16

    s16x8 qfrag[8];
    {
        const unsigned short* qp =
            Qbf + (((size_t)(b * HWSZ + qb + 32 * qt + l31)) << 7) + g * 8;
        #pragma unroll
        for (int fs = 0; fs < 8; ++fs)
            qfrag[fs] = *(const s16x8*)(qp + fs * 16);
    }

    f32x16 acc[4];
    #pragma unroll
    for (int ft = 0; ft < 4; ++ft)
        #pragma unroll
        for (int i = 0; i < 16; ++i) acc[ft][i] = 0.f;

    const unsigned short* Kbase = Kbf  + (((size_t)b * HWSZ) << 7);
    const unsigned short* Vbase = Vtbf + (((size_t)b) << 7) * HWSZ;

    const unsigned short* kSrc = Kbase + (size_t)(jBegin + (t >> 4)) * 128 + (t & 15) * 8;
    const unsigned short* vSrc = Vbase + (size_t)(t >> 3) * HWSZ + jBegin + (t & 7) * 8;
    const int kDst = (t >> 4) * KT_STR + (t & 15) * 8;
    const int vDst = (t >> 3) * VT_STR + (t & 7) * 8;

    {   // prologue: stage tile 0 into buf 0
        unsigned short* Kl = (unsigned short*)smem;
        unsigned short* Vl = (unsigned short*)(smem + KT_BYTES);
        #pragma unroll
        for (int i = 0; i < 4; ++i)
            *(s16x8*)(Kl + kDst + i * 16 * KT_STR) = *(const s16x8*)(kSrc + (size_t)i * 2048);
        #pragma unroll
        for (int i = 0; i < 4; ++i)
            *(s16x8*)(Vl + vDst + i * 32 * VT_STR) = *(const s16x8*)(vSrc + (size_t)i * 32 * HWSZ);
    }
    __syncthreads();

    int c = 0;
    for (int it = 0; it < nt; ++it) {
        const bool pre = (it + 1 < nt);
        const unsigned short* Kl = (const unsigned short*)(smem + c * BUF_BYTES);
        const unsigned short* Vl = (const unsigned short*)(smem + c * BUF_BYTES + KT_BYTES);

        // ---- stage A: QK0 (jt=0), 2 independent chains ----
        s16x8 kf0[8], kf1[8];
        {
            const unsigned short* Krow = Kl + (size_t)l31 * KT_STR + g * 8;
            #pragma unroll
            for (int fs = 0; fs < 8; ++fs)
                kf0[fs] = *(const s16x8*)(Krow + fs * 16);
        }
        f32x16 s0a, s0b;
        #pragma unroll
        for (int i = 0; i < 16; ++i) { s0a[i] = 0.f; s0b[i] = 0.f; }
        __builtin_amdgcn_s_setprio(1);
        #pragma unroll
        for (int fs = 0; fs < 4; ++fs) {
            s0a = __builtin_amdgcn_mfma_f32_32x32x16_bf16(kf0[fs],     qfrag[fs],     s0a, 0, 0, 0);
            s0b = __builtin_amdgcn_mfma_f32_32x32x16_bf16(kf0[fs + 4], qfrag[fs + 4], s0b, 0, 0, 0);
        }
        __builtin_amdgcn_s_setprio(0);

        // K-frags for jt=1 + mid-iter staging issue (independent of QK0)
        {
            const unsigned short* Krow = Kl + (size_t)(32 + l31) * KT_STR + g * 8;
            #pragma unroll
            for (int fs = 0; fs < 8; ++fs)
                kf1[fs] = *(const s16x8*)(Krow + fs * 16);
        }
        s16x8 kr[4], vr[4];
        if (pre) {
            kSrc += 64 * 128;
            vSrc += 64;
            #pragma unroll
            for (int i = 0; i < 4; ++i)
                kr[i] = *(const s16x8*)(kSrc + (size_t)i * 2048);
            #pragma unroll
            for (int i = 0; i < 4; ++i)
                vr[i] = *(const s16x8*)(vSrc + (size_t)i * 32 * HWSZ);
        }

        // ---- stage B: QK1 MFMAs || sigmoid0 (independent -> co-scheduled) ----
        f32x16 s1a, s1b;
        #pragma unroll
        for (int i = 0; i < 16; ++i) { s1a[i] = 0.f; s1b[i] = 0.f; }
        unsigned W0[2][4], W1[2][4];
        #pragma unroll
        for (int fs = 0; fs < 4; ++fs) {
            s1a = __builtin_amdgcn_mfma_f32_32x32x16_bf16(kf1[fs],     qfrag[fs],     s1a, 0, 0, 0);
            s1b = __builtin_amdgcn_mfma_f32_32x32x16_bf16(kf1[fs + 4], qfrag[fs + 4], s1b, 0, 0, 0);
            // one sigmoid quarter (4 values) per fs step, interleaved with MFMA
            const int rg = fs;
            float p0 = sigm2(s0a[4 * rg + 0] + s0b[4 * rg + 0]);
            float p1 = sigm2(s0a[4 * rg + 1] + s0b[4 * rg + 1]);
            float p2 = sigm2(s0a[4 * rg + 2] + s0b[4 * rg + 2]);
            float p3 = sigm2(s0a[4 * rg + 3] + s0b[4 * rg + 3]);
            W0[0][rg] = cvt_pk_bf16(p0, p1);
            W1[0][rg] = cvt_pk_bf16(p2, p3);
        }

        // ---- stage C: PV0 MFMAs || sigmoid1 ----
        __builtin_amdgcn_s_setprio(1);
        #pragma unroll
        for (int s2 = 0; s2 < 2; ++s2) {
            unsigned a0 = W0[0][2 * s2], b0 = W0[0][2 * s2 + 1];
            unsigned a1 = W1[0][2 * s2], b1 = W1[0][2 * s2 + 1];
            asm("v_permlane32_swap_b32 %0, %1" : "+v"(a0), "+v"(b0));
            asm("v_permlane32_swap_b32 %0, %1" : "+v"(a1), "+v"(b1));
            u32x4 pw;
            pw[0] = a0; pw[1] = a1; pw[2] = b0; pw[3] = b1;
            s16x8 pf = __builtin_bit_cast(s16x8, pw);
            #pragma unroll
            for (int ft = 0; ft < 4; ++ft) {
                s16x8 vf = *(const s16x8*)(Vl + (size_t)(32 * ft + l31) * VT_STR + s2 * 16 + g * 8);
                acc[ft] = __builtin_amdgcn_mfma_f32_32x32x16_bf16(pf, vf, acc[ft], 0, 0, 0);
            }
            // two sigmoid quarters of jt1 interleaved with each PV0 half
            #pragma unroll
            for (int h = 0; h < 2; ++h) {
                const int rg = 2 * s2 + h;
                float p0 = sigm2(s1a[4 * rg + 0] + s1b[4 * rg + 0]);
                float p1 = sigm2(s1a[4 * rg + 1] + s1b[4 * rg + 1]);
                float p2 = sigm2(s1a[4 * rg + 2] + s1b[4 * rg + 2]);
                float p3 = sigm2(s1a[4 * rg + 3] + s1b[4 * rg + 3]);
                W0[1][rg] = cvt_pk_bf16(p0, p1);
                W1[1][rg] = cvt_pk_bf16(p2, p3);
            }
        }

        // ---- stage D: PV1 ----
        #pragma unroll
        for (int s2 = 0; s2 < 2; ++s2) {
            unsigned a0 = W0[1][2 * s2], b0 = W0[1][2 * s2 + 1];
            unsigned a1 = W1[1][2 * s2], b1 = W1[1][2 * s2 + 1];
            asm("v_permlane32_swap_b32 %0, %1" : "+v"(a0), "+v"(b0));
            asm("v_permlane32_swap_b32 %0, %1" : "+v"(a1), "+v"(b1));
            u32x4 pw;
            pw[0] = a0; pw[1] = a1; pw[2] = b0; pw[3] = b1;
            s16x8 pf = __builtin_bit_cast(s16x8, pw);
            const int ks = 2 + s2;
            #pragma unroll
            for (int ft = 0; ft < 4; ++ft) {
                s16x8 vf = *(const s16x8*)(Vl + (size_t)(32 * ft + l31) * VT_STR + ks * 16 + g * 8);
                acc[ft] = __builtin_amdgcn_mfma_f32_32x32x16_bf16(pf, vf, acc[ft], 0, 0, 0);
            }
        }
        __builtin_amdgcn_s_setprio(0);

        // ---- write-late into other buffer ----
        if (pre) {
            unsigned short* Kd = (unsigned short*)(smem + (c ^ 1) * BUF_BYTES);
            unsigned short* Vd = (unsigned short*)(smem + (c ^ 1) * BUF_BYTES + KT_BYTES);
            #pragma unroll
            for (int i = 0; i < 4; ++i)
                *(s16x8*)(Kd + kDst + i * 16 * KT_STR) = kr[i];
            #pragma unroll
            for (int i = 0; i < 4; ++i)
                *(s16x8*)(Vd + vDst + i * 32 * VT_STR) = vr[i];
        }
        __syncthreads();
        c ^= 1;
    }

    // ---- epilogue: direct store of wave-private 32q x 128f partial ----
    float* op = outp + (size_t)split * ((size_t)NBATCH * HWSZ * 128);
    #pragma unroll
    for (int ft = 0; ft < 4; ++ft)
    #pragma unroll
    for (int r2 = 0; r2 < 16; ++r2) {
        int row = (r2 & 3) + 8 * (r2 >> 2) + 4 * g;
        int q = qb + 32 * qt + row;
        size_t o = (((size_t)(b * HWSZ + q)) << 7) + 32 * ft + l31;
        op[o] = acc[ft][r2];
    }
}

// ---------------- Kernel 2b: QBLK=64 fallback (2-split / no-split) ----------------
template<bool SPLIT>
__global__ __launch_bounds__(256, 2) void attn_kernel(
    const unsigned short* __restrict__ Kbf,
    const unsigned short* __restrict__ Qbf,
    const unsigned short* __restrict__ Vtbf,
    const float* __restrict__ resid,
    float* __restrict__ outp)
{
    __shared__ __align__(16) char smem[2 * BUF_BYTES];

    const int t    = threadIdx.x;
    const int lane = t & 63;
    const int w    = t >> 6;
    const int qt   = w & 1;
    const int jt   = w >> 1;
    const int l31  = lane & 31;
    const int g    = lane >> 5;

    int bid = blockIdx.x;
    int half = 0;
    if (SPLIT) { half = bid >> 8; bid &= 255; }
    const int b      = bid >> 6;
    const int qb     = (bid & 63) * 64;
    const int jBegin = half * (HWSZ / 2);
    const int nt     = (SPLIT ? HWSZ / 2 : HWSZ) / 64;

    s16x8 qfrag[8];
    {
        const unsigned short* qp =
            Qbf + (((size_t)(b * HWSZ + qb + 32 * qt + l31)) << 7) + g * 8;
        #pragma unroll
        for (int fs = 0; fs < 8; ++fs)
            qfrag[fs] = *(const s16x8*)(qp + fs * 16);
    }

    f32x16 acc[4];
    #pragma unroll
    for (int ft = 0; ft < 4; ++ft)
        #pragma unroll
        for (int i = 0; i < 16; ++i) acc[ft][i] = 0.f;

    const unsigned short* Kbase = Kbf  + (((size_t)b * HWSZ) << 7);
    const unsigned short* Vbase = Vtbf + (((size_t)b) << 7) * HWSZ;

    const unsigned short* kSrc = Kbase + (size_t)(jBegin + (t >> 4)) * 128 + (t & 15) * 8;
    const unsigned short* vSrc = Vbase + (size_t)(t >> 3) * HWSZ + jBegin + (t & 7) * 8;
    const int kDst = (t >> 4) * KT_STR + (t & 15) * 8;
    const int vDst = (t >> 3) * VT_STR + (t & 7) * 8;

    {
        unsigned short* Kl = (unsigned short*)smem;
        unsigned short* Vl = (unsigned short*)(smem + KT_BYTES);
        #pragma unroll
        for (int i = 0; i < 4; ++i)
            *(s16x8*)(Kl + kDst + i * 16 * KT_STR) = *(const s16x8*)(kSrc + (size_t)i * 2048);
        #pragma unroll
        for (int i = 0; i < 4; ++i)
            *(s16x8*)(Vl + vDst + i * 32 * VT_STR) = *(const s16x8*)(vSrc + (size_t)i * 32 * HWSZ);
    }
    __syncthreads();

    int c = 0;
    for (int it = 0; it < nt; ++it) {
        const bool pre = (it + 1 < nt);
        s16x8 kr[4], vr[4];
        if (pre) {
            kSrc += 64 * 128;
            vSrc += 64;
            #pragma unroll
            for (int i = 0; i < 4; ++i)
                kr[i] = *(const s16x8*)(kSrc + (size_t)i * 2048);
            #pragma unroll
            for (int i = 0; i < 4; ++i)
                vr[i] = *(const s16x8*)(vSrc + (size_t)i * 32 * HWSZ);
        }

        const unsigned short* Kl = (const unsigned short*)(smem + c * BUF_BYTES);
        const unsigned short* Vl = (const unsigned short*)(smem + c * BUF_BYTES + KT_BYTES);

        f32x16 sa, sb;
        #pragma unroll
        for (int i = 0; i < 16; ++i) { sa[i] = 0.f; sb[i] = 0.f; }
        const unsigned short* Krow = Kl + (size_t)(32 * jt + l31) * KT_STR + g * 8;
        __builtin_amdgcn_s_setprio(1);
        #pragma unroll
        for (int fs = 0; fs < 4; ++fs) {
            sa = __builtin_amdgcn_mfma_f32_32x32x16_bf16(
                     *(const s16x8*)(Krow + fs * 16), qfrag[fs], sa, 0, 0, 0);
            sb = __builtin_amdgcn_mfma_f32_32x32x16_bf16(
                     *(const s16x8*)(Krow + (fs + 4) * 16), qfrag[fs + 4], sb, 0, 0, 0);
        }
        __builtin_amdgcn_s_setprio(0);

        unsigned W0[4], W1[4];
        #pragma unroll
        for (int rg = 0; rg < 4; ++rg) {
            float p0 = sigm2(sa[4 * rg + 0] + sb[4 * rg + 0]);
            float p1 = sigm2(sa[4 * rg + 1] + sb[4 * rg + 1]);
            float p2 = sigm2(sa[4 * rg + 2] + sb[4 * rg + 2]);
            float p3 = sigm2(sa[4 * rg + 3] + sb[4 * rg + 3]);
            W0[rg] = cvt_pk_bf16(p0, p1);
            W1[rg] = cvt_pk_bf16(p2, p3);
        }

        #pragma unroll
        for (int s2 = 0; s2 < 2; ++s2) {
            unsigned a0 = W0[2 * s2], b0 = W0[2 * s2 + 1];
            unsigned a1 = W1[2 * s2], b1 = W1[2 * s2 + 1];
            asm("v_permlane32_swap_b32 %0, %1" : "+v"(a0), "+v"(b0));
            asm("v_permlane32_swap_b32 %0, %1" : "+v"(a1), "+v"(b1));
            u32x4 pw;
            pw[0] = a0; pw[1] = a1; pw[2] = b0; pw[3] = b1;
            s16x8 pf = __builtin_bit_cast(s16x8, pw);
            const int ks = 2 * jt + s2;
            __builtin_amdgcn_s_setprio(1);
            #pragma unroll
            for (int ft = 0; ft < 4; ++ft) {
                s16x8 vf = *(const s16x8*)(Vl + (size_t)(32 * ft + l31) * VT_STR + ks * 16 + g * 8);
                acc[ft] = __builtin_amdgcn_mfma_f32_32x32x16_bf16(pf, vf, acc[ft], 0, 0, 0);
            }
            __builtin_amdgcn_s_setprio(0);
        }

        if (pre) {
            unsigned short* Kd = (unsigned short*)(smem + (c ^ 1) * BUF_BYTES);
            unsigned short* Vd = (unsigned short*)(smem + (c ^ 1) * BUF_BYTES + KT_BYTES);
            #pragma unroll
            for (int i = 0; i < 4; ++i)
                *(s16x8*)(Kd + kDst + i * 16 * KT_STR) = kr[i];
            #pragma unroll
            for (int i = 0; i < 4; ++i)
                *(s16x8*)(Vd + vDst + i * 32 * VT_STR) = vr[i];
        }
        __syncthreads();
        c ^= 1;
    }

    float* red = (float*)smem;
    if (jt == 1) {
        #pragma unroll
        for (int ft = 0; ft < 4; ++ft)
        #pragma unroll
        for (int r = 0; r < 16; ++r) {
            int row = (r & 3) + 8 * (r >> 2) + 4 * g;
            red[qt * 4096 + row * 128 + 32 * ft + l31] = acc[ft][r];
        }
    }
    __syncthreads();
    if (jt == 0) {
        float* op = outp + (SPLIT ? (size_t)half * ((size_t)NBATCH * HWSZ * 128) : 0);
        #pragma unroll
        for (int ft = 0; ft < 4; ++ft)
        #pragma unroll
        for (int r = 0; r < 16; ++r) {
            int row = (r & 3) + 8 * (r >> 2) + 4 * g;
            float v = acc[ft][r] + red[qt * 4096 + row * 128 + 32 * ft + l31];
            int q = qb + 32 * qt + row;
            size_t o = (((size_t)(b * HWSZ + q)) << 7) + 32 * ft + l31;
            if (SPLIT) op[o] = v;
            else       op[o] = v + resid[o];
        }
    }
}

// ---------------- Kernel 3: partial reduce + residual ----------------
__global__ __launch_bounds__(256, 1) void reduce2_kernel(
    const float* __restrict__ p0, const float* __restrict__ p1, float* outp)
{
    int i = blockIdx.x * 256 + threadIdx.x;
    f32x4 a = ((const f32x4*)p0)[i];
    f32x4 b = ((const f32x4*)p1)[i];
    f32x4 c = ((f32x4*)outp)[i];
    ((f32x4*)outp)[i] = a + b + c;
}

template<int S>
__global__ __launch_bounds__(256, 1) void reduceN_kernel(
    const float* __restrict__ parts, float* __restrict__ outp)
{
    const size_t N4 = (size_t)NBATCH * HWSZ * 128 / 4;
    size_t i = (size_t)blockIdx.x * 256 + threadIdx.x;
    f32x4 s = ((f32x4*)outp)[i];          // xq residual
    #pragma unroll
    for (int k = 0; k < S; ++k)
        s += ((const f32x4*)parts)[i + (size_t)k * N4];
    ((f32x4*)outp)[i] = s;
}

extern "C" void kernel_launch(void* const* d_in, const int* in_sizes, int n_in,
                              void* d_out, int out_size, void* d_ws, size_t ws_size,
                              hipStream_t stream) {
    const float* x  = (const float*)d_in[0];
    const float* y  = (const float*)d_in[1];
    const float* W1 = (const float*)d_in[2];
    const float* b1 = (const float*)d_in[3];
    const float* W2 = (const float*)d_in[4];
    const float* b2 = (const float*)d_in[5];
    float* out = (float*)d_out;

    const size_t NELEM = (size_t)NBATCH * HWSZ * 128;   // 2,097,152
    unsigned short* xq_bf  = (unsigned short*)d_ws;
    unsigned short* yk_bf  = xq_bf + NELEM;
    unsigned short* ykT_bf = yk_bf + NELEM;
    float* part = (float*)(ykT_bf + NELEM);

    proj_kernel<<<(int)(NBATCH * HWSZ / 64), 256, 0, stream>>>(
        x, y, W1, b1, W2, b2, out, xq_bf, yk_bf, ykT_bf);

    if (ws_size >= NELEM * (6 + 16)) {               // 46.1 MB: QBLK=128, 4-split
        attn128_kernel<<<512, 256, 0, stream>>>(xq_bf, yk_bf, ykT_bf, part);
        reduceN_kernel<4><<<(int)(NELEM / 1024), 256, 0, stream>>>(part, out);
    } else if (ws_size >= NELEM * (6 + 8)) {         // 29.4 MB: QBLK=64, 2-split
        attn_kernel<true><<<512, 256, 0, stream>>>(xq_bf, yk_bf, ykT_bf, out, part);
        reduce2_kernel<<<(int)(NELEM / 1024), 256, 0, stream>>>(part, part + NELEM, out);
    } else {
        attn_kernel<false><<<256, 256, 0, stream>>>(xq_bf, yk_bf, ykT_bf, out, out);
    }
}

// Round 12
// 63.914 us; speedup vs baseline: 1.5157x; 1.0301x over previous
//
#include <hip/hip_runtime.h>
#include <hip/hip_bf16.h>
#include <stdint.h>

typedef float f32x16 __attribute__((ext_vector_type(16)));
typedef float f32x4  __attribute__((ext_vector_type(4)));
typedef short s16x8  __attribute__((ext_vector_type(8)));
typedef unsigned int u32x4 __attribute__((ext_vector_type(4)));

#define HWSZ   4096
#define NBATCH 4
#define LOG2E  1.44269504088896340736f

__device__ __forceinline__ unsigned short f2bf(float f) {
    unsigned u = __builtin_bit_cast(unsigned, f);
    u += 0x7FFFu + ((u >> 16) & 1u);          // RTNE
    return (unsigned short)(u >> 16);
}
__device__ __forceinline__ unsigned cvt_pk_bf16(float lo, float hi) {
    __hip_bfloat162 h = __float22bfloat162_rn(make_float2(lo, hi));
    return *reinterpret_cast<unsigned*>(&h);   // v_cvt_pk_bf16_f32; lo -> low 16
}
__device__ __forceinline__ float sigm2(float s) {   // rcp(1+exp2(-s)); K pre-scaled
    return __builtin_amdgcn_rcpf(1.f + __builtin_amdgcn_exp2f(-s));
}
__device__ __forceinline__ float bf_lo(unsigned u) {
    return __builtin_bit_cast(float, u << 16);
}
__device__ __forceinline__ float bf_hi(unsigned u) {
    return __builtin_bit_cast(float, u & 0xFFFF0000u);
}

// ---------------- Kernel 1: MFMA projections ----------------
__global__ __launch_bounds__(256, 1) void proj_kernel(
    const float* __restrict__ x, const float* __restrict__ y,
    const float* __restrict__ W1, const float* __restrict__ b1,
    const float* __restrict__ W2, const float* __restrict__ b2,
    float* __restrict__ xq_f32,
    unsigned short* __restrict__ xq_bf,
    unsigned short* __restrict__ yk_bf,
    unsigned short* __restrict__ ykT_bf)
{
    __shared__ unsigned short Xlds[64][136];
    __shared__ unsigned short Ylds[64][136];
    __shared__ unsigned short Tlds[128][72];

    const int t    = threadIdx.x;
    const int lane = t & 63;
    const int w    = t >> 6;
    const int l31  = lane & 31;
    const int g    = lane >> 5;
    const int r0   = blockIdx.x * 64;
    const int b    = r0 >> 12;
    const int j0   = r0 & (HWSZ - 1);

    #pragma unroll
    for (int i = 0; i < 8; ++i) {
        int li = t + 256 * i;
        int row = li >> 5, c = (li & 31) * 4;
        float4 vx = *(const float4*)(x + (size_t)(r0 + row) * 128 + c);
        float4 vy = *(const float4*)(y + (size_t)(r0 + row) * 128 + c);
        *(uint2*)&Xlds[row][c] = make_uint2(cvt_pk_bf16(vx.x, vx.y), cvt_pk_bf16(vx.z, vx.w));
        *(uint2*)&Ylds[row][c] = make_uint2(cvt_pk_bf16(vy.x, vy.y), cvt_pk_bf16(vy.z, vy.w));
    }
    __syncthreads();

    const int m  = w >> 1;
    const int fh = w & 1;
    const float* Wm = m ? W2 : W1;
    const float* bm = m ? b2 : b1;
    const unsigned short* A0 = m ? &Ylds[0][0] : &Xlds[0][0];

    f32x16 acc[2][2];
    #pragma unroll
    for (int i = 0; i < 16; ++i) {
        acc[0][0][i] = 0.f; acc[0][1][i] = 0.f;
        acc[1][0][i] = 0.f; acc[1][1][i] = 0.f;
    }

    #pragma unroll
    for (int ks = 0; ks < 8; ++ks) {
        s16x8 bfr[2];
        #pragma unroll
        for (int ft = 0; ft < 2; ++ft) {
            const float* wp = Wm + (size_t)(ks * 16 + g * 8) * 128 + fh * 64 + ft * 32 + l31;
            #pragma unroll
            for (int i = 0; i < 8; ++i)
                bfr[ft][i] = (short)f2bf(wp[(size_t)i * 128]);
        }
        #pragma unroll
        for (int rt = 0; rt < 2; ++rt) {
            s16x8 af = *(const s16x8*)(A0 + (size_t)(rt * 32 + l31) * 136 + ks * 16 + g * 8);
            acc[rt][0] = __builtin_amdgcn_mfma_f32_32x32x16_bf16(af, bfr[0], acc[rt][0], 0, 0, 0);
            acc[rt][1] = __builtin_amdgcn_mfma_f32_32x32x16_bf16(af, bfr[1], acc[rt][1], 0, 0, 0);
        }
    }

    const float bias_v[2] = { bm[fh * 64 + l31], bm[fh * 64 + 32 + l31] };

    if (m == 0) {
        #pragma unroll
        for (int rt = 0; rt < 2; ++rt)
        #pragma unroll
        for (int ft = 0; ft < 2; ++ft) {
            int f = fh * 64 + ft * 32 + l31;
            #pragma unroll
            for (int r = 0; r < 16; ++r) {
                int row = rt * 32 + (r & 3) + 8 * (r >> 2) + 4 * g;
                float v = acc[rt][ft][r] + bias_v[ft];
                size_t o = (size_t)(r0 + row) * 128 + f;
                xq_f32[o] = v;
                xq_bf[o]  = f2bf(v * LOG2E);      // K pre-scaled for exp2 sigmoid
            }
        }
    } else {
        #pragma unroll
        for (int rt = 0; rt < 2; ++rt)
        #pragma unroll
        for (int ft = 0; ft < 2; ++ft) {
            int f = fh * 64 + ft * 32 + l31;
            #pragma unroll
            for (int rg = 0; rg < 4; ++rg) {
                float p0 = acc[rt][ft][4 * rg + 0] + bias_v[ft];
                float p1 = acc[rt][ft][4 * rg + 1] + bias_v[ft];
                float p2 = acc[rt][ft][4 * rg + 2] + bias_v[ft];
                float p3 = acc[rt][ft][4 * rg + 3] + bias_v[ft];
                int jb = rt * 32 + 8 * rg + 4 * g;
                *(uint2*)&Tlds[f][jb] = make_uint2(cvt_pk_bf16(p0, p1), cvt_pk_bf16(p2, p3));
                size_t o = (size_t)(r0 + jb) * 128 + f;
                yk_bf[o]       = f2bf(p0);
                yk_bf[o + 128] = f2bf(p1);
                yk_bf[o + 256] = f2bf(p2);
                yk_bf[o + 384] = f2bf(p3);
            }
        }
    }
    __syncthreads();

    {
        int f  = t >> 1;
        int jh = (t & 1) * 32;
        unsigned short* dst = ykT_bf + ((size_t)(b * 128 + f)) * HWSZ + j0 + jh;
        #pragma unroll
        for (int c = 0; c < 4; ++c)
            *(s16x8*)(dst + c * 8) = *(const s16x8*)&Tlds[f][jh + c * 8];
    }
}

// ---------------- shared attention LDS geometry ----------------
#define KT_STR   136
#define VT_STR   72
#define KT_BYTES (64 * KT_STR * 2)     // 17408
#define VT_BYTES (128 * VT_STR * 2)    // 18432
#define BUF_BYTES (KT_BYTES + VT_BYTES)

// ---------------- Kernel 2a: QBLK=128, 4-split, phase-interleaved ----------
// R11 structure + (a) hoisted zero-vector accumulator seed, (b) bf16x2-packed
// partial store (adjacent q-row pairs per u32).
__global__ __launch_bounds__(256, 2) void attn128_kernel(
    const unsigned short* __restrict__ Kbf,   // xq_bf (log2e-scaled) [b][j][128]
    const unsigned short* __restrict__ Qbf,   // yk_bf  [b][q][128]
    const unsigned short* __restrict__ Vtbf,  // ykT_bf [b][128][4096]
    unsigned* __restrict__ outp)              // packed partials (4 x NELEM/2 u32)
{
    __shared__ __align__(16) char smem[2 * BUF_BYTES];

    const int t    = threadIdx.x;
    const int lane = t & 63;
    const int qt   = t >> 6;
    const int l31  = lane & 31;
    const int g    = lane >> 5;

    const int split  = blockIdx.x >> 7;       // 0..3
    const int r      = blockIdx.x & 127;
    const int b      = r >> 5;
    const int qb     = (r & 31) * 128;
    const int jBegin = split * (HWSZ / 4);
    const int nt     = (HWSZ / 4) / 64;       // 16

    s16x8 qfrag[8];
    {
        const unsigned short* qp =
            Qbf + (((size_t)(b * HWSZ + qb + 32 * qt + l31)) << 7) + g * 8;
        #pragma unroll
        for (int fs = 0; fs < 8; ++fs)
            qfrag[fs] = *(const s16x8*)(qp + fs * 16);
    }

    f32x16 acc[4];
    #pragma unroll
    for (int ft = 0; ft < 4; ++ft)
        #pragma unroll
        for (int i = 0; i < 16; ++i) acc[ft][i] = 0.f;

    f32x16 zv;                                 // hoisted zero seed for QK chains
    #pragma unroll
    for (int i = 0; i < 16; ++i) zv[i] = 0.f;

    const unsigned short* Kbase = Kbf  + (((size_t)b * HWSZ) << 7);
    const unsigned short* Vbase = Vtbf + (((size_t)b) << 7) * HWSZ;

    const unsigned short* kSrc = Kbase + (size_t)(jBegin + (t >> 4)) * 128 + (t & 15) * 8;
    const unsigned short* vSrc = Vbase + (size_t)(t >> 3) * HWSZ + jBegin + (t & 7) * 8;
    const int kDst = (t >> 4) * KT_STR + (t & 15) * 8;
    const int vDst = (t >> 3) * VT_STR + (t & 7) * 8;

    {   // prologue: stage tile 0 into buf 0
        unsigned short* Kl = (unsigned short*)smem;
        unsigned short* Vl = (unsigned short*)(smem + KT_BYTES);
        #pragma unroll
        for (int i = 0; i < 4; ++i)
            *(s16x8*)(Kl + kDst + i * 16 * KT_STR) = *(const s16x8*)(kSrc + (size_t)i * 2048);
        #pragma unroll
        for (int i = 0; i < 4; ++i)
            *(s16x8*)(Vl + vDst + i * 32 * VT_STR) = *(const s16x8*)(vSrc + (size_t)i * 32 * HWSZ);
    }
    __syncthreads();

    int c = 0;
    for (int it = 0; it < nt; ++it) {
        const bool pre = (it + 1 < nt);
        const unsigned short* Kl = (const unsigned short*)(smem + c * BUF_BYTES);
        const unsigned short* Vl = (const unsigned short*)(smem + c * BUF_BYTES + KT_BYTES);

        // ---- stage A: QK0 (jt=0), 2 independent chains seeded from zv ----
        s16x8 kf0[8], kf1[8];
        {
            const unsigned short* Krow = Kl + (size_t)l31 * KT_STR + g * 8;
            #pragma unroll
            for (int fs = 0; fs < 8; ++fs)
                kf0[fs] = *(const s16x8*)(Krow + fs * 16);
        }
        f32x16 s0a, s0b;
        __builtin_amdgcn_s_setprio(1);
        #pragma unroll
        for (int fs = 0; fs < 4; ++fs) {
            s0a = __builtin_amdgcn_mfma_f32_32x32x16_bf16(kf0[fs],     qfrag[fs],
                      fs == 0 ? zv : s0a, 0, 0, 0);
            s0b = __builtin_amdgcn_mfma_f32_32x32x16_bf16(kf0[fs + 4], qfrag[fs + 4],
                      fs == 0 ? zv : s0b, 0, 0, 0);
        }
        __builtin_amdgcn_s_setprio(0);

        // K-frags for jt=1 + mid-iter staging issue (independent of QK0)
        {
            const unsigned short* Krow = Kl + (size_t)(32 + l31) * KT_STR + g * 8;
            #pragma unroll
            for (int fs = 0; fs < 8; ++fs)
                kf1[fs] = *(const s16x8*)(Krow + fs * 16);
        }
        s16x8 kr[4], vr[4];
        if (pre) {
            kSrc += 64 * 128;
            vSrc += 64;
            #pragma unroll
            for (int i = 0; i < 4; ++i)
                kr[i] = *(const s16x8*)(kSrc + (size_t)i * 2048);
            #pragma unroll
            for (int i = 0; i < 4; ++i)
                vr[i] = *(const s16x8*)(vSrc + (size_t)i * 32 * HWSZ);
        }

        // ---- stage B: QK1 MFMAs || sigmoid0 ----
        f32x16 s1a, s1b;
        unsigned W0[2][4], W1[2][4];
        #pragma unroll
        for (int fs = 0; fs < 4; ++fs) {
            s1a = __builtin_amdgcn_mfma_f32_32x32x16_bf16(kf1[fs],     qfrag[fs],
                      fs == 0 ? zv : s1a, 0, 0, 0);
            s1b = __builtin_amdgcn_mfma_f32_32x32x16_bf16(kf1[fs + 4], qfrag[fs + 4],
                      fs == 0 ? zv : s1b, 0, 0, 0);
            const int rg = fs;
            float p0 = sigm2(s0a[4 * rg + 0] + s0b[4 * rg + 0]);
            float p1 = sigm2(s0a[4 * rg + 1] + s0b[4 * rg + 1]);
            float p2 = sigm2(s0a[4 * rg + 2] + s0b[4 * rg + 2]);
            float p3 = sigm2(s0a[4 * rg + 3] + s0b[4 * rg + 3]);
            W0[0][rg] = cvt_pk_bf16(p0, p1);
            W1[0][rg] = cvt_pk_bf16(p2, p3);
        }

        // ---- stage C: PV0 MFMAs || sigmoid1 ----
        __builtin_amdgcn_s_setprio(1);
        #pragma unroll
        for (int s2 = 0; s2 < 2; ++s2) {
            unsigned a0 = W0[0][2 * s2], b0 = W0[0][2 * s2 + 1];
            unsigned a1 = W1[0][2 * s2], b1 = W1[0][2 * s2 + 1];
            asm("v_permlane32_swap_b32 %0, %1" : "+v"(a0), "+v"(b0));
            asm("v_permlane32_swap_b32 %0, %1" : "+v"(a1), "+v"(b1));
            u32x4 pw;
            pw[0] = a0; pw[1] = a1; pw[2] = b0; pw[3] = b1;
            s16x8 pf = __builtin_bit_cast(s16x8, pw);
            #pragma unroll
            for (int ft = 0; ft < 4; ++ft) {
                s16x8 vf = *(const s16x8*)(Vl + (size_t)(32 * ft + l31) * VT_STR + s2 * 16 + g * 8);
                acc[ft] = __builtin_amdgcn_mfma_f32_32x32x16_bf16(pf, vf, acc[ft], 0, 0, 0);
            }
            #pragma unroll
            for (int h = 0; h < 2; ++h) {
                const int rg = 2 * s2 + h;
                float p0 = sigm2(s1a[4 * rg + 0] + s1b[4 * rg + 0]);
                float p1 = sigm2(s1a[4 * rg + 1] + s1b[4 * rg + 1]);
                float p2 = sigm2(s1a[4 * rg + 2] + s1b[4 * rg + 2]);
                float p3 = sigm2(s1a[4 * rg + 3] + s1b[4 * rg + 3]);
                W0[1][rg] = cvt_pk_bf16(p0, p1);
                W1[1][rg] = cvt_pk_bf16(p2, p3);
            }
        }

        // ---- stage D: PV1 ----
        #pragma unroll
        for (int s2 = 0; s2 < 2; ++s2) {
            unsigned a0 = W0[1][2 * s2], b0 = W0[1][2 * s2 + 1];
            unsigned a1 = W1[1][2 * s2], b1 = W1[1][2 * s2 + 1];
            asm("v_permlane32_swap_b32 %0, %1" : "+v"(a0), "+v"(b0));
            asm("v_permlane32_swap_b32 %0, %1" : "+v"(a1), "+v"(b1));
            u32x4 pw;
            pw[0] = a0; pw[1] = a1; pw[2] = b0; pw[3] = b1;
            s16x8 pf = __builtin_bit_cast(s16x8, pw);
            const int ks = 2 + s2;
            #pragma unroll
            for (int ft = 0; ft < 4; ++ft) {
                s16x8 vf = *(const s16x8*)(Vl + (size_t)(32 * ft + l31) * VT_STR + ks * 16 + g * 8);
                acc[ft] = __builtin_amdgcn_mfma_f32_32x32x16_bf16(pf, vf, acc[ft], 0, 0, 0);
            }
        }
        __builtin_amdgcn_s_setprio(0);

        // ---- write-late into other buffer ----
        if (pre) {
            unsigned short* Kd = (unsigned short*)(smem + (c ^ 1) * BUF_BYTES);
            unsigned short* Vd = (unsigned short*)(smem + (c ^ 1) * BUF_BYTES + KT_BYTES);
            #pragma unroll
            for (int i = 0; i < 4; ++i)
                *(s16x8*)(Kd + kDst + i * 16 * KT_STR) = kr[i];
            #pragma unroll
            for (int i = 0; i < 4; ++i)
                *(s16x8*)(Vd + vDst + i * 32 * VT_STR) = vr[i];
        }
        __syncthreads();
        c ^= 1;
    }

    // ---- epilogue: bf16x2-packed partial (row pairs r2, r2+1) ----
    unsigned* op = outp + (size_t)split * ((size_t)NBATCH * HWSZ * 64);
    #pragma unroll
    for (int ft = 0; ft < 4; ++ft)
    #pragma unroll
    for (int pr = 0; pr < 8; ++pr) {
        int r2 = 2 * pr;
        int row = (r2 & 3) + 8 * (r2 >> 2) + 4 * g;      // even
        int q = qb + 32 * qt + row;
        unsigned v = cvt_pk_bf16(acc[ft][r2], acc[ft][r2 + 1]);
        op[((size_t)(b * HWSZ + q) >> 1) * 128 + 32 * ft + l31] = v;
    }
}

// ---------------- Kernel 2b: QBLK=64 fallback (2-split / no-split) ----------------
template<bool SPLIT>
__global__ __launch_bounds__(256, 2) void attn_kernel(
    const unsigned short* __restrict__ Kbf,
    const unsigned short* __restrict__ Qbf,
    const unsigned short* __restrict__ Vtbf,
    const float* __restrict__ resid,
    float* __restrict__ outp)
{
    __shared__ __align__(16) char smem[2 * BUF_BYTES];

    const int t    = threadIdx.x;
    const int lane = t & 63;
    const int w    = t >> 6;
    const int qt   = w & 1;
    const int jt   = w >> 1;
    const int l31  = lane & 31;
    const int g    = lane >> 5;

    int bid = blockIdx.x;
    int half = 0;
    if (SPLIT) { half = bid >> 8; bid &= 255; }
    const int b      = bid >> 6;
    const int qb     = (bid & 63) * 64;
    const int jBegin = half * (HWSZ / 2);
    const int nt     = (SPLIT ? HWSZ / 2 : HWSZ) / 64;

    s16x8 qfrag[8];
    {
        const unsigned short* qp =
            Qbf + (((size_t)(b * HWSZ + qb + 32 * qt + l31)) << 7) + g * 8;
        #pragma unroll
        for (int fs = 0; fs < 8; ++fs)
            qfrag[fs] = *(const s16x8*)(qp + fs * 16);
    }

    f32x16 acc[4];
    #pragma unroll
    for (int ft = 0; ft < 4; ++ft)
        #pragma unroll
        for (int i = 0; i < 16; ++i) acc[ft][i] = 0.f;

    const unsigned short* Kbase = Kbf  + (((size_t)b * HWSZ) << 7);
    const unsigned short* Vbase = Vtbf + (((size_t)b) << 7) * HWSZ;

    const unsigned short* kSrc = Kbase + (size_t)(jBegin + (t >> 4)) * 128 + (t & 15) * 8;
    const unsigned short* vSrc = Vbase + (size_t)(t >> 3) * HWSZ + jBegin + (t & 7) * 8;
    const int kDst = (t >> 4) * KT_STR + (t & 15) * 8;
    const int vDst = (t >> 3) * VT_STR + (t & 7) * 8;

    {
        unsigned short* Kl = (unsigned short*)smem;
        unsigned short* Vl = (unsigned short*)(smem + KT_BYTES);
        #pragma unroll
        for (int i = 0; i < 4; ++i)
            *(s16x8*)(Kl + kDst + i * 16 * KT_STR) = *(const s16x8*)(kSrc + (size_t)i * 2048);
        #pragma unroll
        for (int i = 0; i < 4; ++i)
            *(s16x8*)(Vl + vDst + i * 32 * VT_STR) = *(const s16x8*)(vSrc + (size_t)i * 32 * HWSZ);
    }
    __syncthreads();

    int c = 0;
    for (int it = 0; it < nt; ++it) {
        const bool pre = (it + 1 < nt);
        s16x8 kr[4], vr[4];
        if (pre) {
            kSrc += 64 * 128;
            vSrc += 64;
            #pragma unroll
            for (int i = 0; i < 4; ++i)
                kr[i] = *(const s16x8*)(kSrc + (size_t)i * 2048);
            #pragma unroll
            for (int i = 0; i < 4; ++i)
                vr[i] = *(const s16x8*)(vSrc + (size_t)i * 32 * HWSZ);
        }

        const unsigned short* Kl = (const unsigned short*)(smem + c * BUF_BYTES);
        const unsigned short* Vl = (const unsigned short*)(smem + c * BUF_BYTES + KT_BYTES);

        f32x16 sa, sb;
        #pragma unroll
        for (int i = 0; i < 16; ++i) { sa[i] = 0.f; sb[i] = 0.f; }
        const unsigned short* Krow = Kl + (size_t)(32 * jt + l31) * KT_STR + g * 8;
        __builtin_amdgcn_s_setprio(1);
        #pragma unroll
        for (int fs = 0; fs < 4; ++fs) {
            sa = __builtin_amdgcn_mfma_f32_32x32x16_bf16(
                     *(const s16x8*)(Krow + fs * 16), qfrag[fs], sa, 0, 0, 0);
            sb = __builtin_amdgcn_mfma_f32_32x32x16_bf16(
                     *(const s16x8*)(Krow + (fs + 4) * 16), qfrag[fs + 4], sb, 0, 0, 0);
        }
        __builtin_amdgcn_s_setprio(0);

        unsigned W0[4], W1[4];
        #pragma unroll
        for (int rg = 0; rg < 4; ++rg) {
            float p0 = sigm2(sa[4 * rg + 0] + sb[4 * rg + 0]);
            float p1 = sigm2(sa[4 * rg + 1] + sb[4 * rg + 1]);
            float p2 = sigm2(sa[4 * rg + 2] + sb[4 * rg + 2]);
            float p3 = sigm2(sa[4 * rg + 3] + sb[4 * rg + 3]);
            W0[rg] = cvt_pk_bf16(p0, p1);
            W1[rg] = cvt_pk_bf16(p2, p3);
        }

        #pragma unroll
        for (int s2 = 0; s2 < 2; ++s2) {
            unsigned a0 = W0[2 * s2], b0 = W0[2 * s2 + 1];
            unsigned a1 = W1[2 * s2], b1 = W1[2 * s2 + 1];
            asm("v_permlane32_swap_b32 %0, %1" : "+v"(a0), "+v"(b0));
            asm("v_permlane32_swap_b32 %0, %1" : "+v"(a1), "+v"(b1));
            u32x4 pw;
            pw[0] = a0; pw[1] = a1; pw[2] = b0; pw[3] = b1;
            s16x8 pf = __builtin_bit_cast(s16x8, pw);
            const int ks = 2 * jt + s2;
            __builtin_amdgcn_s_setprio(1);
            #pragma unroll
            for (int ft = 0; ft < 4; ++ft) {
                s16x8 vf = *(const s16x8*)(Vl + (size_t)(32 * ft + l31) * VT_STR + ks * 16 + g * 8);
                acc[ft] = __builtin_amdgcn_mfma_f32_32x32x16_bf16(pf, vf, acc[ft], 0, 0, 0);
            }
            __builtin_amdgcn_s_setprio(0);
        }

        if (pre) {
            unsigned short* Kd = (unsigned short*)(smem + (c ^ 1) * BUF_BYTES);
            unsigned short* Vd = (unsigned short*)(smem + (c ^ 1) * BUF_BYTES + KT_BYTES);
            #pragma unroll
            for (int i = 0; i < 4; ++i)
                *(s16x8*)(Kd + kDst + i * 16 * KT_STR) = kr[i];
            #pragma unroll
            for (int i = 0; i < 4; ++i)
                *(s16x8*)(Vd + vDst + i * 32 * VT_STR) = vr[i];
        }
        __syncthreads();
        c ^= 1;
    }

    float* red = (float*)smem;
    if (jt == 1) {
        #pragma unroll
        for (int ft = 0; ft < 4; ++ft)
        #pragma unroll
        for (int r = 0; r < 16; ++r) {
            int row = (r & 3) + 8 * (r >> 2) + 4 * g;
            red[qt * 4096 + row * 128 + 32 * ft + l31] = acc[ft][r];
        }
    }
    __syncthreads();
    if (jt == 0) {
        float* op = outp + (SPLIT ? (size_t)half * ((size_t)NBATCH * HWSZ * 128) : 0);
        #pragma unroll
        for (int ft = 0; ft < 4; ++ft)
        #pragma unroll
        for (int r = 0; r < 16; ++r) {
            int row = (r & 3) + 8 * (r >> 2) + 4 * g;
            float v = acc[ft][r] + red[qt * 4096 + row * 128 + 32 * ft + l31];
            int q = qb + 32 * qt + row;
            size_t o = (((size_t)(b * HWSZ + q)) << 7) + 32 * ft + l31;
            if (SPLIT) op[o] = v;
            else       op[o] = v + resid[o];
        }
    }
}

// ---------------- Kernel 3: partial reduce + residual ----------------
__global__ __launch_bounds__(256, 1) void reduce2_kernel(
    const float* __restrict__ p0, const float* __restrict__ p1, float* outp)
{
    int i = blockIdx.x * 256 + threadIdx.x;
    f32x4 a = ((const f32x4*)p0)[i];
    f32x4 b = ((const f32x4*)p1)[i];
    f32x4 c = ((f32x4*)outp)[i];
    ((f32x4*)outp)[i] = a + b + c;
}

// bf16x2-packed 4-way reduce: each thread handles 4 u32 (= 4 f-cols x 2 rows)
__global__ __launch_bounds__(256, 1) void reduce4bf_kernel(
    const unsigned* __restrict__ parts, float* __restrict__ outp)
{
    const size_t NU = (size_t)NBATCH * HWSZ * 64;     // u32 per split
    size_t j0 = ((size_t)blockIdx.x * 256 + threadIdx.x) * 4;
    f32x4 lo, hi;
    #pragma unroll
    for (int e = 0; e < 4; ++e) { lo[e] = 0.f; hi[e] = 0.f; }
    #pragma unroll
    for (int k = 0; k < 4; ++k) {
        u32x4 v = *(const u32x4*)(parts + k * NU + j0);
        #pragma unroll
        for (int e = 0; e < 4; ++e) {
            lo[e] += bf_lo(v[e]);
            hi[e] += bf_hi(v[e]);
        }
    }
    size_t p  = j0 >> 7;
    int    f0 = (int)(j0 & 127);
    size_t o0 = (p * 2) * 128 + f0;
    f32x4 r0 = *(const f32x4*)(outp + o0);
    f32x4 r1 = *(const f32x4*)(outp + o0 + 128);
    *(f32x4*)(outp + o0)       = r0 + lo;
    *(f32x4*)(outp + o0 + 128) = r1 + hi;
}

extern "C" void kernel_launch(void* const* d_in, const int* in_sizes, int n_in,
                              void* d_out, int out_size, void* d_ws, size_t ws_size,
                              hipStream_t stream) {
    const float* x  = (const float*)d_in[0];
    const float* y  = (const float*)d_in[1];
    const float* W1 = (const float*)d_in[2];
    const float* b1 = (const float*)d_in[3];
    const float* W2 = (const float*)d_in[4];
    const float* b2 = (const float*)d_in[5];
    float* out = (float*)d_out;

    const size_t NELEM = (size_t)NBATCH * HWSZ * 128;   // 2,097,152
    unsigned short* xq_bf  = (unsigned short*)d_ws;
    unsigned short* yk_bf  = xq_bf + NELEM;
    unsigned short* ykT_bf = yk_bf + NELEM;
    float* part = (float*)(ykT_bf + NELEM);

    proj_kernel<<<(int)(NBATCH * HWSZ / 64), 256, 0, stream>>>(
        x, y, W1, b1, W2, b2, out, xq_bf, yk_bf, ykT_bf);

    if (ws_size >= NELEM * (6 + 16)) {               // 4-split, bf16-packed partials
        attn128_kernel<<<512, 256, 0, stream>>>(xq_bf, yk_bf, ykT_bf, (unsigned*)part);
        reduce4bf_kernel<<<(int)(NELEM / 2 / 4 / 256), 256, 0, stream>>>((unsigned*)part, out);
    } else if (ws_size >= NELEM * (6 + 8)) {         // 29.4 MB: QBLK=64, 2-split
        attn_kernel<true><<<512, 256, 0, stream>>>(xq_bf, yk_bf, ykT_bf, out, part);
        reduce2_kernel<<<(int)(NELEM / 1024), 256, 0, stream>>>(part, part + NELEM, out);
    } else {
        attn_kernel<false><<<256, 256, 0, stream>>>(xq_bf, yk_bf, ykT_bf, out, out);
    }
}

// Round 13
// 60.777 us; speedup vs baseline: 1.5939x; 1.0516x over previous
//
#include <hip/hip_runtime.h>
#include <hip/hip_bf16.h>
#include <stdint.h>

typedef float f32x16 __attribute__((ext_vector_type(16)));
typedef float f32x4  __attribute__((ext_vector_type(4)));
typedef short s16x8  __attribute__((ext_vector_type(8)));
typedef unsigned int u32x4 __attribute__((ext_vector_type(4)));

#define HWSZ   4096
#define NBATCH 4
#define LOG2E  1.44269504088896340736f

__device__ __forceinline__ unsigned short f2bf(float f) {
    unsigned u = __builtin_bit_cast(unsigned, f);
    u += 0x7FFFu + ((u >> 16) & 1u);          // RTNE
    return (unsigned short)(u >> 16);
}
__device__ __forceinline__ unsigned cvt_pk_bf16(float lo, float hi) {
    __hip_bfloat162 h = __float22bfloat162_rn(make_float2(lo, hi));
    return *reinterpret_cast<unsigned*>(&h);   // v_cvt_pk_bf16_f32; lo -> low 16
}
__device__ __forceinline__ float sigm2(float s) {   // rcp(1+exp2(-s)); K pre-scaled
    return __builtin_amdgcn_rcpf(1.f + __builtin_amdgcn_exp2f(-s));
}
__device__ __forceinline__ float bf_lo(unsigned u) {
    return __builtin_bit_cast(float, u << 16);
}
__device__ __forceinline__ float bf_hi(unsigned u) {
    return __builtin_bit_cast(float, u & 0xFFFF0000u);
}
__device__ __forceinline__ float bf2f(unsigned short u) {
    return __builtin_bit_cast(float, (unsigned)u << 16);
}

// ---------------- Kernel 1: MFMA projections (32 rows/WG, 512 WGs) ----------
// xq = x@W1+b1 -> residual (f32 d_out if WF32, else bf16 xqu) + xq_bf (LOG2E-scaled K)
// yk = y@W2+b2 -> yk_bf + ykT_bf (transposed)
template<bool WF32>
__global__ __launch_bounds__(256, 2) void proj_kernel(
    const float* __restrict__ x, const float* __restrict__ y,
    const float* __restrict__ W1, const float* __restrict__ b1,
    const float* __restrict__ W2, const float* __restrict__ b2,
    float* __restrict__ xq_f32,               // WF32 path (fallback)
    unsigned short* __restrict__ xqu_bf,      // !WF32 path (bf16 residual)
    unsigned short* __restrict__ xq_bf,
    unsigned short* __restrict__ yk_bf,
    unsigned short* __restrict__ ykT_bf)
{
    __shared__ unsigned short Xlds[32][136];
    __shared__ unsigned short Ylds[32][136];
    __shared__ unsigned short Tlds[128][40];  // yk^T tile [f][j0..j0+31], +8 pad

    const int t    = threadIdx.x;
    const int lane = t & 63;
    const int w    = t >> 6;
    const int l31  = lane & 31;
    const int g    = lane >> 5;
    const int r0   = blockIdx.x * 32;
    const int b    = r0 >> 12;
    const int j0   = r0 & (HWSZ - 1);

    #pragma unroll
    for (int i = 0; i < 4; ++i) {
        int li = t + 256 * i;                  // 1024 float4 chunks = 32x128
        int row = li >> 5, c = (li & 31) * 4;
        float4 vx = *(const float4*)(x + (size_t)(r0 + row) * 128 + c);
        float4 vy = *(const float4*)(y + (size_t)(r0 + row) * 128 + c);
        *(uint2*)&Xlds[row][c] = make_uint2(cvt_pk_bf16(vx.x, vx.y), cvt_pk_bf16(vx.z, vx.w));
        *(uint2*)&Ylds[row][c] = make_uint2(cvt_pk_bf16(vy.x, vy.y), cvt_pk_bf16(vy.z, vy.w));
    }
    __syncthreads();

    const int m  = w >> 1;                     // 0: xq  1: yk
    const int fh = w & 1;                      // column half
    const float* Wm = m ? W2 : W1;
    const float* bm = m ? b2 : b1;
    const unsigned short* A0 = m ? &Ylds[0][0] : &Xlds[0][0];

    f32x16 acc[2];
    #pragma unroll
    for (int i = 0; i < 16; ++i) { acc[0][i] = 0.f; acc[1][i] = 0.f; }

    #pragma unroll
    for (int ks = 0; ks < 8; ++ks) {
        s16x8 bfr[2];
        #pragma unroll
        for (int ft = 0; ft < 2; ++ft) {
            const float* wp = Wm + (size_t)(ks * 16 + g * 8) * 128 + fh * 64 + ft * 32 + l31;
            #pragma unroll
            for (int i = 0; i < 8; ++i)
                bfr[ft][i] = (short)f2bf(wp[(size_t)i * 128]);
        }
        s16x8 af = *(const s16x8*)(A0 + (size_t)l31 * 136 + ks * 16 + g * 8);
        acc[0] = __builtin_amdgcn_mfma_f32_32x32x16_bf16(af, bfr[0], acc[0], 0, 0, 0);
        acc[1] = __builtin_amdgcn_mfma_f32_32x32x16_bf16(af, bfr[1], acc[1], 0, 0, 0);
    }

    const float bias_v[2] = { bm[fh * 64 + l31], bm[fh * 64 + 32 + l31] };

    if (m == 0) {
        #pragma unroll
        for (int ft = 0; ft < 2; ++ft) {
            int f = fh * 64 + ft * 32 + l31;
            #pragma unroll
            for (int r = 0; r < 16; ++r) {
                int row = (r & 3) + 8 * (r >> 2) + 4 * g;
                float v = acc[ft][r] + bias_v[ft];
                size_t o = (size_t)(r0 + row) * 128 + f;
                if (WF32) xq_f32[o] = v;
                else      xqu_bf[o] = f2bf(v);
                xq_bf[o] = f2bf(v * LOG2E);       // K pre-scaled for exp2 sigmoid
            }
        }
    } else {
        #pragma unroll
        for (int ft = 0; ft < 2; ++ft) {
            int f = fh * 64 + ft * 32 + l31;
            #pragma unroll
            for (int rg = 0; rg < 4; ++rg) {
                float p0 = acc[ft][4 * rg + 0] + bias_v[ft];
                float p1 = acc[ft][4 * rg + 1] + bias_v[ft];
                float p2 = acc[ft][4 * rg + 2] + bias_v[ft];
                float p3 = acc[ft][4 * rg + 3] + bias_v[ft];
                int jb = 8 * rg + 4 * g;          // rows jb..jb+3
                *(uint2*)&Tlds[f][jb] = make_uint2(cvt_pk_bf16(p0, p1), cvt_pk_bf16(p2, p3));
                size_t o = (size_t)(r0 + jb) * 128 + f;
                yk_bf[o]       = f2bf(p0);
                yk_bf[o + 128] = f2bf(p1);
                yk_bf[o + 256] = f2bf(p2);
                yk_bf[o + 384] = f2bf(p3);
            }
        }
    }
    __syncthreads();

    {   // cooperative ykT store (whole 64B-line halves per thread)
        int f  = t >> 1;
        int jh = (t & 1) * 16;
        unsigned short* dst = ykT_bf + ((size_t)(b * 128 + f)) * HWSZ + j0 + jh;
        #pragma unroll
        for (int c = 0; c < 2; ++c)
            *(s16x8*)(dst + c * 8) = *(const s16x8*)&Tlds[f][jh + c * 8];
    }
}

// ---------------- shared attention LDS geometry ----------------
#define KT_STR   136
#define VT_STR   72
#define KT_BYTES (64 * KT_STR * 2)     // 17408
#define VT_BYTES (128 * VT_STR * 2)    // 18432
#define BUF_BYTES (KT_BYTES + VT_BYTES)

// ---------------- Kernel 2a: QBLK=128, 4-split, phase-interleaved (R12) ------
__global__ __launch_bounds__(256, 2) void attn128_kernel(
    const unsigned short* __restrict__ Kbf,   // xq_bf (log2e-scaled) [b][j][128]
    const unsigned short* __restrict__ Qbf,   // yk_bf  [b][q][128]
    const unsigned short* __restrict__ Vtbf,  // ykT_bf [b][128][4096]
    unsigned* __restrict__ outp)              // packed partials (4 x NELEM/2 u32)
{
    __shared__ __align__(16) char smem[2 * BUF_BYTES];

    const int t    = threadIdx.x;
    const int lane = t & 63;
    const int qt   = t >> 6;
    const int l31  = lane & 31;
    const int g    = lane >> 5;

    const int split  = blockIdx.x >> 7;       // 0..3
    const int r      = blockIdx.x & 127;
    const int b      = r >> 5;
    const int qb     = (r & 31) * 128;
    const int jBegin = split * (HWSZ / 4);
    const int nt     = (HWSZ / 4) / 64;       // 16

    s16x8 qfrag[8];
    {
        const unsigned short* qp =
            Qbf + (((size_t)(b * HWSZ + qb + 32 * qt + l31)) << 7) + g * 8;
        #pragma unroll
        for (int fs = 0; fs < 8; ++fs)
            qfrag[fs] = *(const s16x8*)(qp + fs * 16);
    }

    f32x16 acc[4];
    #pragma unroll
    for (int ft = 0; ft < 4; ++ft)
        #pragma unroll
        for (int i = 0; i < 16; ++i) acc[ft][i] = 0.f;

    f32x16 zv;                                 // hoisted zero seed for QK chains
    #pragma unroll
    for (int i = 0; i < 16; ++i) zv[i] = 0.f;

    const unsigned short* Kbase = Kbf  + (((size_t)b * HWSZ) << 7);
    const unsigned short* Vbase = Vtbf + (((size_t)b) << 7) * HWSZ;

    const unsigned short* kSrc = Kbase + (size_t)(jBegin + (t >> 4)) * 128 + (t & 15) * 8;
    const unsigned short* vSrc = Vbase + (size_t)(t >> 3) * HWSZ + jBegin + (t & 7) * 8;
    const int kDst = (t >> 4) * KT_STR + (t & 15) * 8;
    const int vDst = (t >> 3) * VT_STR + (t & 7) * 8;

    {   // prologue: stage tile 0 into buf 0
        unsigned short* Kl = (unsigned short*)smem;
        unsigned short* Vl = (unsigned short*)(smem + KT_BYTES);
        #pragma unroll
        for (int i = 0; i < 4; ++i)
            *(s16x8*)(Kl + kDst + i * 16 * KT_STR) = *(const s16x8*)(kSrc + (size_t)i * 2048);
        #pragma unroll
        for (int i = 0; i < 4; ++i)
            *(s16x8*)(Vl + vDst + i * 32 * VT_STR) = *(const s16x8*)(vSrc + (size_t)i * 32 * HWSZ);
    }
    __syncthreads();

    int c = 0;
    for (int it = 0; it < nt; ++it) {
        const bool pre = (it + 1 < nt);
        const unsigned short* Kl = (const unsigned short*)(smem + c * BUF_BYTES);
        const unsigned short* Vl = (const unsigned short*)(smem + c * BUF_BYTES + KT_BYTES);

        // ---- stage A: QK0 (jt=0), 2 independent chains seeded from zv ----
        s16x8 kf0[8], kf1[8];
        {
            const unsigned short* Krow = Kl + (size_t)l31 * KT_STR + g * 8;
            #pragma unroll
            for (int fs = 0; fs < 8; ++fs)
                kf0[fs] = *(const s16x8*)(Krow + fs * 16);
        }
        f32x16 s0a, s0b;
        __builtin_amdgcn_s_setprio(1);
        #pragma unroll
        for (int fs = 0; fs < 4; ++fs) {
            s0a = __builtin_amdgcn_mfma_f32_32x32x16_bf16(kf0[fs],     qfrag[fs],
                      fs == 0 ? zv : s0a, 0, 0, 0);
            s0b = __builtin_amdgcn_mfma_f32_32x32x16_bf16(kf0[fs + 4], qfrag[fs + 4],
                      fs == 0 ? zv : s0b, 0, 0, 0);
        }
        __builtin_amdgcn_s_setprio(0);

        // K-frags for jt=1 + mid-iter staging issue (independent of QK0)
        {
            const unsigned short* Krow = Kl + (size_t)(32 + l31) * KT_STR + g * 8;
            #pragma unroll
            for (int fs = 0; fs < 8; ++fs)
                kf1[fs] = *(const s16x8*)(Krow + fs * 16);
        }
        s16x8 kr[4], vr[4];
        if (pre) {
            kSrc += 64 * 128;
            vSrc += 64;
            #pragma unroll
            for (int i = 0; i < 4; ++i)
                kr[i] = *(const s16x8*)(kSrc + (size_t)i * 2048);
            #pragma unroll
            for (int i = 0; i < 4; ++i)
                vr[i] = *(const s16x8*)(vSrc + (size_t)i * 32 * HWSZ);
        }

        // ---- stage B: QK1 MFMAs || sigmoid0 ----
        f32x16 s1a, s1b;
        unsigned W0[2][4], W1[2][4];
        #pragma unroll
        for (int fs = 0; fs < 4; ++fs) {
            s1a = __builtin_amdgcn_mfma_f32_32x32x16_bf16(kf1[fs],     qfrag[fs],
                      fs == 0 ? zv : s1a, 0, 0, 0);
            s1b = __builtin_amdgcn_mfma_f32_32x32x16_bf16(kf1[fs + 4], qfrag[fs + 4],
                      fs == 0 ? zv : s1b, 0, 0, 0);
            const int rg = fs;
            float p0 = sigm2(s0a[4 * rg + 0] + s0b[4 * rg + 0]);
            float p1 = sigm2(s0a[4 * rg + 1] + s0b[4 * rg + 1]);
            float p2 = sigm2(s0a[4 * rg + 2] + s0b[4 * rg + 2]);
            float p3 = sigm2(s0a[4 * rg + 3] + s0b[4 * rg + 3]);
            W0[0][rg] = cvt_pk_bf16(p0, p1);
            W1[0][rg] = cvt_pk_bf16(p2, p3);
        }

        // ---- stage C: PV0 MFMAs || sigmoid1 ----
        __builtin_amdgcn_s_setprio(1);
        #pragma unroll
        for (int s2 = 0; s2 < 2; ++s2) {
            unsigned a0 = W0[0][2 * s2], b0 = W0[0][2 * s2 + 1];
            unsigned a1 = W1[0][2 * s2], b1 = W1[0][2 * s2 + 1];
            asm("v_permlane32_swap_b32 %0, %1" : "+v"(a0), "+v"(b0));
            asm("v_permlane32_swap_b32 %0, %1" : "+v"(a1), "+v"(b1));
            u32x4 pw;
            pw[0] = a0; pw[1] = a1; pw[2] = b0; pw[3] = b1;
            s16x8 pf = __builtin_bit_cast(s16x8, pw);
            #pragma unroll
            for (int ft = 0; ft < 4; ++ft) {
                s16x8 vf = *(const s16x8*)(Vl + (size_t)(32 * ft + l31) * VT_STR + s2 * 16 + g * 8);
                acc[ft] = __builtin_amdgcn_mfma_f32_32x32x16_bf16(pf, vf, acc[ft], 0, 0, 0);
            }
            #pragma unroll
            for (int h = 0; h < 2; ++h) {
                const int rg = 2 * s2 + h;
                float p0 = sigm2(s1a[4 * rg + 0] + s1b[4 * rg + 0]);
                float p1 = sigm2(s1a[4 * rg + 1] + s1b[4 * rg + 1]);
                float p2 = sigm2(s1a[4 * rg + 2] + s1b[4 * rg + 2]);
                float p3 = sigm2(s1a[4 * rg + 3] + s1b[4 * rg + 3]);
                W0[1][rg] = cvt_pk_bf16(p0, p1);
                W1[1][rg] = cvt_pk_bf16(p2, p3);
            }
        }

        // ---- stage D: PV1 ----
        #pragma unroll
        for (int s2 = 0; s2 < 2; ++s2) {
            unsigned a0 = W0[1][2 * s2], b0 = W0[1][2 * s2 + 1];
            unsigned a1 = W1[1][2 * s2], b1 = W1[1][2 * s2 + 1];
            asm("v_permlane32_swap_b32 %0, %1" : "+v"(a0), "+v"(b0));
            asm("v_permlane32_swap_b32 %0, %1" : "+v"(a1), "+v"(b1));
            u32x4 pw;
            pw[0] = a0; pw[1] = a1; pw[2] = b0; pw[3] = b1;
            s16x8 pf = __builtin_bit_cast(s16x8, pw);
            const int ks = 2 + s2;
            #pragma unroll
            for (int ft = 0; ft < 4; ++ft) {
                s16x8 vf = *(const s16x8*)(Vl + (size_t)(32 * ft + l31) * VT_STR + ks * 16 + g * 8);
                acc[ft] = __builtin_amdgcn_mfma_f32_32x32x16_bf16(pf, vf, acc[ft], 0, 0, 0);
            }
        }
        __builtin_amdgcn_s_setprio(0);

        // ---- write-late into other buffer ----
        if (pre) {
            unsigned short* Kd = (unsigned short*)(smem + (c ^ 1) * BUF_BYTES);
            unsigned short* Vd = (unsigned short*)(smem + (c ^ 1) * BUF_BYTES + KT_BYTES);
            #pragma unroll
            for (int i = 0; i < 4; ++i)
                *(s16x8*)(Kd + kDst + i * 16 * KT_STR) = kr[i];
            #pragma unroll
            for (int i = 0; i < 4; ++i)
                *(s16x8*)(Vd + vDst + i * 32 * VT_STR) = vr[i];
        }
        __syncthreads();
        c ^= 1;
    }

    // ---- epilogue: bf16x2-packed partial (row pairs r2, r2+1) ----
    unsigned* op = outp + (size_t)split * ((size_t)NBATCH * HWSZ * 64);
    #pragma unroll
    for (int ft = 0; ft < 4; ++ft)
    #pragma unroll
    for (int pr = 0; pr < 8; ++pr) {
        int r2 = 2 * pr;
        int row = (r2 & 3) + 8 * (r2 >> 2) + 4 * g;      // even
        int q = qb + 32 * qt + row;
        unsigned v = cvt_pk_bf16(acc[ft][r2], acc[ft][r2 + 1]);
        op[((size_t)(b * HWSZ + q) >> 1) * 128 + 32 * ft + l31] = v;
    }
}

// ---------------- Kernel 2b: QBLK=64 fallback (2-split / no-split) ----------------
template<bool SPLIT>
__global__ __launch_bounds__(256, 2) void attn_kernel(
    const unsigned short* __restrict__ Kbf,
    const unsigned short* __restrict__ Qbf,
    const unsigned short* __restrict__ Vtbf,
    const float* __restrict__ resid,
    float* __restrict__ outp)
{
    __shared__ __align__(16) char smem[2 * BUF_BYTES];

    const int t    = threadIdx.x;
    const int lane = t & 63;
    const int w    = t >> 6;
    const int qt   = w & 1;
    const int jt   = w >> 1;
    const int l31  = lane & 31;
    const int g    = lane >> 5;

    int bid = blockIdx.x;
    int half = 0;
    if (SPLIT) { half = bid >> 8; bid &= 255; }
    const int b      = bid >> 6;
    const int qb     = (bid & 63) * 64;
    const int jBegin = half * (HWSZ / 2);
    const int nt     = (SPLIT ? HWSZ / 2 : HWSZ) / 64;

    s16x8 qfrag[8];
    {
        const unsigned short* qp =
            Qbf + (((size_t)(b * HWSZ + qb + 32 * qt + l31)) << 7) + g * 8;
        #pragma unroll
        for (int fs = 0; fs < 8; ++fs)
            qfrag[fs] = *(const s16x8*)(qp + fs * 16);
    }

    f32x16 acc[4];
    #pragma unroll
    for (int ft = 0; ft < 4; ++ft)
        #pragma unroll
        for (int i = 0; i < 16; ++i) acc[ft][i] = 0.f;

    const unsigned short* Kbase = Kbf  + (((size_t)b * HWSZ) << 7);
    const unsigned short* Vbase = Vtbf + (((size_t)b) << 7) * HWSZ;

    const unsigned short* kSrc = Kbase + (size_t)(jBegin + (t >> 4)) * 128 + (t & 15) * 8;
    const unsigned short* vSrc = Vbase + (size_t)(t >> 3) * HWSZ + jBegin + (t & 7) * 8;
    const int kDst = (t >> 4) * KT_STR + (t & 15) * 8;
    const int vDst = (t >> 3) * VT_STR + (t & 7) * 8;

    {
        unsigned short* Kl = (unsigned short*)smem;
        unsigned short* Vl = (unsigned short*)(smem + KT_BYTES);
        #pragma unroll
        for (int i = 0; i < 4; ++i)
            *(s16x8*)(Kl + kDst + i * 16 * KT_STR) = *(const s16x8*)(kSrc + (size_t)i * 2048);
        #pragma unroll
        for (int i = 0; i < 4; ++i)
            *(s16x8*)(Vl + vDst + i * 32 * VT_STR) = *(const s16x8*)(vSrc + (size_t)i * 32 * HWSZ);
    }
    __syncthreads();

    int c = 0;
    for (int it = 0; it < nt; ++it) {
        const bool pre = (it + 1 < nt);
        s16x8 kr[4], vr[4];
        if (pre) {
            kSrc += 64 * 128;
            vSrc += 64;
            #pragma unroll
            for (int i = 0; i < 4; ++i)
                kr[i] = *(const s16x8*)(kSrc + (size_t)i * 2048);
            #pragma unroll
            for (int i = 0; i < 4; ++i)
                vr[i] = *(const s16x8*)(vSrc + (size_t)i * 32 * HWSZ);
        }

        const unsigned short* Kl = (const unsigned short*)(smem + c * BUF_BYTES);
        const unsigned short* Vl = (const unsigned short*)(smem + c * BUF_BYTES + KT_BYTES);

        f32x16 sa, sb;
        #pragma unroll
        for (int i = 0; i < 16; ++i) { sa[i] = 0.f; sb[i] = 0.f; }
        const unsigned short* Krow = Kl + (size_t)(32 * jt + l31) * KT_STR + g * 8;
        __builtin_amdgcn_s_setprio(1);
        #pragma unroll
        for (int fs = 0; fs < 4; ++fs) {
            sa = __builtin_amdgcn_mfma_f32_32x32x16_bf16(
                     *(const s16x8*)(Krow + fs * 16), qfrag[fs], sa, 0, 0, 0);
            sb = __builtin_amdgcn_mfma_f32_32x32x16_bf16(
                     *(const s16x8*)(Krow + (fs + 4) * 16), qfrag[fs + 4], sb, 0, 0, 0);
        }
        __builtin_amdgcn_s_setprio(0);

        unsigned W0[4], W1[4];
        #pragma unroll
        for (int rg = 0; rg < 4; ++rg) {
            float p0 = sigm2(sa[4 * rg + 0] + sb[4 * rg + 0]);
            float p1 = sigm2(sa[4 * rg + 1] + sb[4 * rg + 1]);
            float p2 = sigm2(sa[4 * rg + 2] + sb[4 * rg + 2]);
            float p3 = sigm2(sa[4 * rg + 3] + sb[4 * rg + 3]);
            W0[rg] = cvt_pk_bf16(p0, p1);
            W1[rg] = cvt_pk_bf16(p2, p3);
        }

        #pragma unroll
        for (int s2 = 0; s2 < 2; ++s2) {
            unsigned a0 = W0[2 * s2], b0 = W0[2 * s2 + 1];
            unsigned a1 = W1[2 * s2], b1 = W1[2 * s2 + 1];
            asm("v_permlane32_swap_b32 %0, %1" : "+v"(a0), "+v"(b0));
            asm("v_permlane32_swap_b32 %0, %1" : "+v"(a1), "+v"(b1));
            u32x4 pw;
            pw[0] = a0; pw[1] = a1; pw[2] = b0; pw[3] = b1;
            s16x8 pf = __builtin_bit_cast(s16x8, pw);
            const int ks = 2 * jt + s2;
            __builtin_amdgcn_s_setprio(1);
            #pragma unroll
            for (int ft = 0; ft < 4; ++ft) {
                s16x8 vf = *(const s16x8*)(Vl + (size_t)(32 * ft + l31) * VT_STR + ks * 16 + g * 8);
                acc[ft] = __builtin_amdgcn_mfma_f32_32x32x16_bf16(pf, vf, acc[ft], 0, 0, 0);
            }
            __builtin_amdgcn_s_setprio(0);
        }

        if (pre) {
            unsigned short* Kd = (unsigned short*)(smem + (c ^ 1) * BUF_BYTES);
            unsigned short* Vd = (unsigned short*)(smem + (c ^ 1) * BUF_BYTES + KT_BYTES);
            #pragma unroll
            for (int i = 0; i < 4; ++i)
                *(s16x8*)(Kd + kDst + i * 16 * KT_STR) = kr[i];
            #pragma unroll
            for (int i = 0; i < 4; ++i)
                *(s16x8*)(Vd + vDst + i * 32 * VT_STR) = vr[i];
        }
        __syncthreads();
        c ^= 1;
    }

    float* red = (float*)smem;
    if (jt == 1) {
        #pragma unroll
        for (int ft = 0; ft < 4; ++ft)
        #pragma unroll
        for (int r = 0; r < 16; ++r) {
            int row = (r & 3) + 8 * (r >> 2) + 4 * g;
            red[qt * 4096 + row * 128 + 32 * ft + l31] = acc[ft][r];
        }
    }
    __syncthreads();
    if (jt == 0) {
        float* op = outp + (SPLIT ? (size_t)half * ((size_t)NBATCH * HWSZ * 128) : 0);
        #pragma unroll
        for (int ft = 0; ft < 4; ++ft)
        #pragma unroll
        for (int r = 0; r < 16; ++r) {
            int row = (r & 3) + 8 * (r >> 2) + 4 * g;
            float v = acc[ft][r] + red[qt * 4096 + row * 128 + 32 * ft + l31];
            int q = qb + 32 * qt + row;
            size_t o = (((size_t)(b * HWSZ + q)) << 7) + 32 * ft + l31;
            if (SPLIT) op[o] = v;
            else       op[o] = v + resid[o];
        }
    }
}

// ---------------- Kernel 3: partial reduce + residual ----------------
__global__ __launch_bounds__(256, 1) void reduce2_kernel(
    const float* __restrict__ p0, const float* __restrict__ p1, float* outp)
{
    int i = blockIdx.x * 256 + threadIdx.x;
    f32x4 a = ((const f32x4*)p0)[i];
    f32x4 b = ((const f32x4*)p1)[i];
    f32x4 c = ((f32x4*)outp)[i];
    ((f32x4*)outp)[i] = a + b + c;
}

// bf16x2-packed 4-way reduce + bf16 residual: thread = 4 u32 (4 f-cols x 2 rows)
__global__ __launch_bounds__(256, 1) void reduce4bf_kernel(
    const unsigned* __restrict__ parts, const unsigned short* __restrict__ xqu,
    float* __restrict__ outp)
{
    const size_t NU = (size_t)NBATCH * HWSZ * 64;     // u32 per split
    size_t j0 = ((size_t)blockIdx.x * 256 + threadIdx.x) * 4;
    f32x4 lo, hi;
    #pragma unroll
    for (int e = 0; e < 4; ++e) { lo[e] = 0.f; hi[e] = 0.f; }
    #pragma unroll
    for (int k = 0; k < 4; ++k) {
        u32x4 v = *(const u32x4*)(parts + k * NU + j0);
        #pragma unroll
        for (int e = 0; e < 4; ++e) {
            lo[e] += bf_lo(v[e]);
            hi[e] += bf_hi(v[e]);
        }
    }
    size_t p  = j0 >> 7;
    int    f0 = (int)(j0 & 127);
    size_t o0 = (p * 2) * 128 + f0;
    const ushort4 r0 = *(const ushort4*)(xqu + o0);
    const ushort4 r1 = *(const ushort4*)(xqu + o0 + 128);
    lo[0] += bf2f(r0.x); lo[1] += bf2f(r0.y); lo[2] += bf2f(r0.z); lo[3] += bf2f(r0.w);
    hi[0] += bf2f(r1.x); hi[1] += bf2f(r1.y); hi[2] += bf2f(r1.z); hi[3] += bf2f(r1.w);
    *(f32x4*)(outp + o0)       = lo;
    *(f32x4*)(outp + o0 + 128) = hi;
}

extern "C" void kernel_launch(void* const* d_in, const int* in_sizes, int n_in,
                              void* d_out, int out_size, void* d_ws, size_t ws_size,
                              hipStream_t stream) {
    const float* x  = (const float*)d_in[0];
    const float* y  = (const float*)d_in[1];
    const float* W1 = (const float*)d_in[2];
    const float* b1 = (const float*)d_in[3];
    const float* W2 = (const float*)d_in[4];
    const float* b2 = (const float*)d_in[5];
    float* out = (float*)d_out;

    const size_t NELEM = (size_t)NBATCH * HWSZ * 128;   // 2,097,152
    unsigned short* xq_bf  = (unsigned short*)d_ws;
    unsigned short* yk_bf  = xq_bf + NELEM;
    unsigned short* ykT_bf = yk_bf + NELEM;
    unsigned short* xqu_bf = ykT_bf + NELEM;             // main path bf16 residual
    unsigned* partu = (unsigned*)(xqu_bf + NELEM);       // 4 x NELEM/2 u32
    float* part = (float*)(ykT_bf + NELEM);              // fallback f32 partials

    if (ws_size >= NELEM * 16) {                 // main: 4-split, bf16 partials+residual
        proj_kernel<false><<<(int)(NBATCH * HWSZ / 32), 256, 0, stream>>>(
            x, y, W1, b1, W2, b2, nullptr, xqu_bf, xq_bf, yk_bf, ykT_bf);
        attn128_kernel<<<512, 256, 0, stream>>>(xq_bf, yk_bf, ykT_bf, partu);
        reduce4bf_kernel<<<(int)(NELEM / 2048), 256, 0, stream>>>(partu, xqu_bf, out);
    } else if (ws_size >= NELEM * 14) {          // QBLK=64, 2-split (f32 partials)
        proj_kernel<true><<<(int)(NBATCH * HWSZ / 32), 256, 0, stream>>>(
            x, y, W1, b1, W2, b2, out, nullptr, xq_bf, yk_bf, ykT_bf);
        attn_kernel<true><<<512, 256, 0, stream>>>(xq_bf, yk_bf, ykT_bf, out, part);
        reduce2_kernel<<<(int)(NELEM / 1024), 256, 0, stream>>>(part, part + NELEM, out);
    } else {
        proj_kernel<true><<<(int)(NBATCH * HWSZ / 32), 256, 0, stream>>>(
            x, y, W1, b1, W2, b2, out, nullptr, xq_bf, yk_bf, ykT_bf);
        attn_kernel<false><<<256, 256, 0, stream>>>(xq_bf, yk_bf, ykT_bf, out, out);
    }
}